// Round 26
// baseline (388.828 us; speedup 1.0000x reference)
//
#include <hip/hip_runtime.h>
#include <hip/hip_bf16.h>
#include <cstdint>
#include <cstddef>

constexpr int NF = 100000;
constexpr int NA = 400;
constexpr int NC = 30;
constexpr int NN = NF + NA + NC;     // 100430
constexpr int D  = 256;
constexpr int DD = D * D;            // 65536
constexpr int E  = 250000;
constexpr int NSL = 128;             // slices for r0/r2 counting sort
constexpr int FBLK = (NF + 127) / 128;   // 782 flight-encoder blocks
constexpr int TAILB = (NA + NC + 7) / 8; // 54 scalar-tail blocks
constexpr int F13B = (2 * E + 511) / 512; // 977 csr_fill13 blocks (512 thr)
constexpr int AGGB = NA * 4 + NC * 64;    // 3520 agg chunks

// K1 block ranges
constexpr int K1_HIST_END = 2 * NSL;                       // 256
constexpr int K1_DEG_END  = K1_HIST_END + (2 * E + 255) / 256;  // 2210
constexpr int K1_WS0_END  = K1_DEG_END + 256;              // 2466
constexpr int K1_WS1_END  = K1_WS0_END + 256;              // 2722
constexpr int K1_WR0_END  = K1_WS1_END + 1024;             // 3746
constexpr int K1_WR1_END  = K1_WR0_END + 1024;             // 4770

// work_kernel block ranges: encoder | tail(+y0) | fill13 | fill02
constexpr int W_ENC_END  = FBLK;                 // 782
constexpr int W_TAIL_END = W_ENC_END + TAILB;    // 836
constexpr int W_F13_END  = W_TAIL_END + F13B;    // 1813
constexpr int W_TOTAL    = W_F13_END + 2 * NSL;  // 2069

typedef __attribute__((ext_vector_type(8))) short bf16x8;
typedef __attribute__((ext_vector_type(4))) float f32x4;
typedef __attribute__((ext_vector_type(8))) ushort u16x8;

__device__ inline ushort f2bf(float f) {
    __hip_bfloat16 h = __float2bfloat16(f);
    return __builtin_bit_cast(ushort, h);
}
__device__ inline float bf2f(ushort u) {
    __hip_bfloat16 h = __builtin_bit_cast(__hip_bfloat16, u);
    return __bfloat162float(h);
}

// async global->LDS, 16B per lane: LDS dest = base + lane*16 (wave-linear)
__device__ inline void gload_lds16(const ushort* g, ushort* l) {
    __builtin_amdgcn_global_load_lds(
        (const __attribute__((address_space(1))) void*)g,
        (__attribute__((address_space(3))) void*)l, 16, 0, 0);
}

// ==== K1: hist02 + deg_count + wsplit(x2) + wr(x2), co-scheduled ============
__global__ __launch_bounds__(256) void prep_kernel(
    const int* __restrict__ dst0, const int* __restrict__ dst2,
    int* __restrict__ bh0, int* __restrict__ bh2,
    float* __restrict__ aggz,
    const float* __restrict__ Wf, ushort* __restrict__ WfTH, ushort* __restrict__ WfTL,
    const int* __restrict__ dst1, const int* __restrict__ dst3,
    int* __restrict__ deg1, int* __restrict__ deg3,
    const float* __restrict__ root0, ushort* __restrict__ WtH0, ushort* __restrict__ WtL0,
    const float* __restrict__ root1, ushort* __restrict__ WtH1, ushort* __restrict__ WtL1,
    const float* __restrict__ basis0, const float* __restrict__ comp0, float* __restrict__ wr0,
    const float* __restrict__ basis1, const float* __restrict__ comp1, float* __restrict__ wr1)
{
    __shared__ int hist[NA];
    const int b = blockIdx.x;
    const int t = threadIdx.x;
    if (b < K1_HIST_END) {
        for (int i = b * 256 + t; i < (NA + NC) * D; i += K1_HIST_END * 256)
            aggz[i] = 0.f;
        if (b < 32) {
            float wv = Wf[(size_t)b * D + t];
            ushort hi = f2bf(wv);
            WfTH[(size_t)t * 32 + b] = hi;
            WfTL[(size_t)t * 32 + b] = f2bf(wv - bf2f(hi));
        }
        bool isR2 = (b >= NSL);
        int sl = isR2 ? b - NSL : b;
        const int* dst = isR2 ? dst2 : dst0;
        int nb = isR2 ? NC : NA;
        for (int i = t; i < nb; i += 256) hist[i] = 0;
        __syncthreads();
        int lo = (int)((long long)E * sl / NSL);
        int hi = (int)((long long)E * (sl + 1) / NSL);
        for (int e = lo + t; e < hi; e += 256)
            atomicAdd(&hist[dst[e]], 1);
        __syncthreads();
        int* bh = isR2 ? (bh2 + sl * NC) : (bh0 + sl * NA);
        for (int i = t; i < nb; i += 256) bh[i] = hist[i];
    } else if (b < K1_DEG_END) {
        int idx = (b - K1_HIST_END) * 256 + t;
        if (idx < 2 * E) {
            if (idx < E) atomicAdd(&deg1[dst1[idx]], 1);
            else         atomicAdd(&deg3[dst3[idx - E]], 1);
        }
    } else if (b < K1_WS0_END) {
        int n = b - K1_DEG_END;
        float w = root0[(size_t)t * D + n];
        ushort hi = f2bf(w);
        WtH0[(size_t)n * D + t] = hi;
        WtL0[(size_t)n * D + t] = f2bf(w - bf2f(hi));
    } else if (b < K1_WS1_END) {
        int n = b - K1_WS0_END;
        float w = root1[(size_t)t * D + n];
        ushort hi = f2bf(w);
        WtH1[(size_t)n * D + t] = hi;
        WtL1[(size_t)n * D + t] = f2bf(w - bf2f(hi));
    } else if (b < K1_WR0_END) {
        int idx = (b - K1_WS1_END) * 256 + t;
        int r = idx >> 16;
        int io = idx & (DD - 1);
        wr0[idx] = comp0[r * 3 + 0] * basis0[io]
                 + comp0[r * 3 + 1] * basis0[DD + io]
                 + comp0[r * 3 + 2] * basis0[2 * DD + io];
    } else {
        int idx = (b - K1_WR0_END) * 256 + t;
        int r = idx >> 16;
        int io = idx & (DD - 1);
        wr1[idx] = comp1[r * 3 + 0] * basis1[io]
                 + comp1[r * 3 + 1] * basis1[DD + io]
                 + comp1[r * 3 + 2] * basis1[2 * DD + io];
    }
}

// ==== K2: scanA (blocks 0..195) + scan02 (block 196), co-scheduled ==========
__global__ __launch_bounds__(1024) void scan_kernel(
    const int* __restrict__ deg1, const int* __restrict__ deg3,
    int* __restrict__ bsum,
    int* __restrict__ bh0, int* __restrict__ bh2,
    int* __restrict__ rp0, int* __restrict__ rp2,
    float* __restrict__ inv0, float* __restrict__ inv2)
{
    __shared__ int s[1024];
    __shared__ int tot[512];
    __shared__ int exc[512];
    const int b = blockIdx.x;
    const int t = threadIdx.x;
    if (b < 196) {
        bool isR3 = (b >= 98);
        const int* deg = isR3 ? deg3 : deg1;
        int chunk = isR3 ? b - 98 : b;
        int i = chunk * 1024 + t;
        int v = (i < NF) ? deg[i] : 0;
        s[t] = v;
        __syncthreads();
        for (int ofs = 512; ofs > 0; ofs >>= 1) {
            if (t < ofs) s[t] += s[t + ofs];
            __syncthreads();
        }
        if (t == 0) bsum[(isR3 ? 128 : 0) + chunk] = s[0];
        return;
    }
    int cnt = 0;
    if (t < NA) {
        int ss = 0;
        for (int sl = 0; sl < NSL; ++sl) {
            int v = bh0[sl * NA + t]; bh0[sl * NA + t] = ss; ss += v;
        }
        cnt = ss;
    } else if (t < NA + NC) {
        int bin = t - NA; int ss = 0;
        for (int sl = 0; sl < NSL; ++sl) {
            int v = bh2[sl * NC + bin]; bh2[sl * NC + bin] = ss; ss += v;
        }
        cnt = ss;
    }
    if (t < 512) tot[t] = cnt;
    __syncthreads();
    for (int ofs = 1; ofs < 512; ofs <<= 1) {
        int v = 0;
        if (t < 512 && t >= ofs) v = tot[t - ofs];
        __syncthreads();
        if (t < 512) tot[t] += v;
        __syncthreads();
    }
    if (t < 512) {
        int ex = tot[t] - cnt;
        if (t < NA) {
            exc[t] = ex;
            rp0[t] = ex;
            inv0[t] = 1.0f / (float)(cnt > 1 ? cnt : 1);
            if (t == 0) { rp0[NA] = E; rp2[NC] = E; }
        } else if (t < NA + NC) {
            exc[t] = ex - E;
            rp2[t - NA] = ex - E;
            inv2[t - NA] = 1.0f / (float)(cnt > 1 ? cnt : 1);
        } else exc[t] = 0;
    }
    __syncthreads();
    for (int idx = t; idx < NSL * NA; idx += 1024) {
        int sl = idx / NA; int bin = idx - sl * NA;
        bh0[idx] += exc[bin];
    }
    for (int idx = t; idx < NSL * NC; idx += 1024) {
        int sl = idx / NC; int bin = idx - sl * NC;
        bh2[idx] += exc[NA + bin];
    }
}

// ==== scanC (with inlined scanB), standalone -------------------------------
__global__ __launch_bounds__(1024) void scanC_kernel(
    const int* __restrict__ deg1, const int* __restrict__ deg3,
    const int* __restrict__ bsum,
    int* __restrict__ rp1, int* __restrict__ rp3,
    int* __restrict__ cu1, int* __restrict__ cu3,
    float* __restrict__ inv1, float* __restrict__ inv3)
{
    __shared__ int s[1024];
    __shared__ int s2[256];
    int t = threadIdx.x;
    int b = blockIdx.x;                    // 0..195
    int vb = 0;
    if (t < 256) {
        vb = ((t & 127) < 98) ? bsum[t] : 0;
        s2[t] = vb;
    }
    __syncthreads();
    for (int ofs = 1; ofs < 128; ofs <<= 1) {
        int a = 0;
        if (t < 256 && (t & 127) >= ofs) a = s2[t - ofs];
        __syncthreads();
        if (t < 256) s2[t] += a;
        __syncthreads();
    }
    if (t < 256) s2[t] -= vb;          // exclusive
    __syncthreads();
    const int* deg; int* rp; int* cu; float* inv; int chunk; int prefix;
    if (b < 98) { deg = deg1; rp = rp1; cu = cu1; inv = inv1; chunk = b;      prefix = s2[chunk]; }
    else        { deg = deg3; rp = rp3; cu = cu3; inv = inv3; chunk = b - 98; prefix = s2[128 + chunk]; }
    int i = chunk * 1024 + t;
    int v = (i < NF) ? deg[i] : 0;
    s[t] = v;
    __syncthreads();
    for (int ofs = 1; ofs < 1024; ofs <<= 1) {
        int a = (t >= ofs) ? s[t - ofs] : 0;
        __syncthreads();
        s[t] += a;
        __syncthreads();
    }
    int ex = prefix + s[t] - v;
    if (i < NF) {
        rp[i] = ex;
        cu[i] = ex;
        inv[i] = 1.0f / (float)(v > 1 ? v : 1);
    }
    if (i == 0) rp[NF] = E;
}

// ==== work_kernel: encoder + tail(+y0) + csr_fill13 + fill02, co-sched ======
__global__ __launch_bounds__(512) void work_kernel(
    const float* __restrict__ xf,
    const ushort* __restrict__ WtH8, const ushort* __restrict__ WtL8,
    const float* __restrict__ bfl,
    const float* __restrict__ xa, const float* __restrict__ Wa, const float* __restrict__ ba,
    const float* __restrict__ xc, const float* __restrict__ Wc, const float* __restrict__ bc,
    ushort* __restrict__ hH,
    const int* __restrict__ src1, const int* __restrict__ dst1,
    const int* __restrict__ src3, const int* __restrict__ dst3,
    int* __restrict__ cu1, int* __restrict__ cu3,
    int* __restrict__ csr1, int* __restrict__ csr3,
    const int* __restrict__ src0, const int* __restrict__ dst0,
    const int* __restrict__ src2, const int* __restrict__ dst2,
    const int* __restrict__ bh0, const int* __restrict__ bh2,
    int* __restrict__ csr0, int* __restrict__ csr2,
    const float* __restrict__ wr0, float* __restrict__ y0)
{
    __shared__ __align__(16) ushort lds[20480];            // 40960 B
    const int t = threadIdx.x;
    const int b = blockIdx.x;
    if (b >= W_F13_END) {
        // ---- fill02 (512 threads, LDS cursor)
        int bb = b - W_F13_END;
        int* cur = (int*)lds;
        bool isR2 = (bb >= NSL);
        int sl = isR2 ? bb - NSL : bb;
        const int* src = isR2 ? src2 : src0;
        const int* dst = isR2 ? dst2 : dst0;
        const int* bh  = isR2 ? (bh2 + sl * NC) : (bh0 + sl * NA);
        int* csr       = isR2 ? csr2 : csr0;
        int nb = isR2 ? NC : NA;
        for (int i = t; i < nb; i += 512) cur[i] = bh[i];
        __syncthreads();
        int lo = (int)((long long)E * sl / NSL);
        int hi = (int)((long long)E * (sl + 1) / NSL);
        for (int e = lo + t; e < hi; e += 512) {
            int pos = atomicAdd(&cur[dst[e]], 1);
            csr[pos] = src[e];
        }
        return;
    }
    if (b >= W_TAIL_END) {
        // ---- csr_fill13
        int idx = (b - W_TAIL_END) * 512 + t;
        if (idx < 2 * E) {
            if (idx < E) {
                int pos = atomicAdd(&cu1[dst1[idx]], 1);
                csr1[pos] = src1[idx];
            } else {
                int e = idx - E;
                int pos = atomicAdd(&cu3[dst3[e]], 1);
                csr3[pos] = src3[e];
            }
        }
        return;
    }
    if (b >= W_ENC_END) {
        // ---- airports + carriers scalar encode, then y0 = h @ Wr0[rel]
        float* hrow = (float*)lds;           // 8 x 256 floats = 8 KB
        int c = t & 255;
        int i0 = t >> 8;
        int base = (b - W_ENC_END) * 8;
        for (int i = i0; i < 8; i += 2) {
            int row = base + i;
            float val = 0.f;
            if (row < NA + NC) {
                float acc;
                if (row < NA) {
                    const float* xr = xa + (size_t)row * 16;
                    acc = ba[c];
                    #pragma unroll
                    for (int k = 0; k < 16; ++k) acc += xr[k] * Wa[k * D + c];
                } else {
                    const float* xr = xc + (size_t)(row - NA) * 8;
                    acc = bc[c];
                    #pragma unroll
                    for (int k = 0; k < 8; ++k) acc += xr[k] * Wc[k * D + c];
                }
                ushort hv = f2bf(fmaxf(acc, 0.f));
                hH[(size_t)(NF + row) * D + c] = hv;
                val = bf2f(hv);
            }
            hrow[i * 256 + c] = val;
        }
        __syncthreads();
        for (int i = i0; i < 8; i += 2) {
            int row = base + i;
            if (row >= NA + NC) break;
            const float* W = wr0 + (size_t)((row < NA) ? 1 : 3) * DD;
            const float* hr = hrow + i * 256;
            float acc = 0.f;
            #pragma unroll 8
            for (int k = 0; k < D; ++k) acc += hr[k] * W[k * D + c];
            y0[(size_t)row * D + c] = acc;
        }
        return;
    }
    // ---- flight MFMA encoder
    constexpr int AOFF = 0, WHOFF = 4096, WLOFF = 12288;   // ushort offsets
    const int row0 = b * 128;
    const int w = t >> 6, lane = t & 63;     // 8 waves
    const int wm = w >> 2, wn = w & 3;       // 2x4 grid, 64 rows x 64 cols/wave
    const int lr = lane & 15;
    const int lk = lane >> 4;
    {
        int r = t >> 2;                      // 0..127
        int seg = (t & 3) * 8;               // 0,8,16,24
        int gr = row0 + r; if (gr >= NF) gr = NF - 1;
        const float* xr = xf + (size_t)gr * 32 + seg;
        float4 a0 = *(const float4*)xr;
        float4 a1 = *(const float4*)(xr + 4);
        u16x8 bb;
        bb[0] = f2bf(a0.x); bb[1] = f2bf(a0.y); bb[2] = f2bf(a0.z); bb[3] = f2bf(a0.w);
        bb[4] = f2bf(a1.x); bb[5] = f2bf(a1.y); bb[6] = f2bf(a1.z); bb[7] = f2bf(a1.w);
        int g = r >> 4, rr = r & 15, kg = seg >> 3;
        *(u16x8*)(lds + AOFF + g * 512 + (rr + 16 * kg) * 8) = bb;
    }
    #pragma unroll
    for (int i = 0; i < 4; ++i) {
        int u = w * 4 + i;                   // 0..31
        int plane = u >> 4, g = u & 15;
        const ushort* src = (plane ? WtL8 : WtH8) + ((size_t)(g * 16 + lr)) * 32 + lk * 8;
        ushort* dst = lds + (plane ? WLOFF : WHOFF) + g * 512;
        gload_lds16(src, dst);
    }
    __syncthreads();
    f32x4 acc[4][4] = {};
    bf16x8 bhv[4], blv[4];
    #pragma unroll
    for (int ni = 0; ni < 4; ++ni) {
        int off = (wn * 4 + ni) * 512 + lane * 8;
        bhv[ni] = *(const bf16x8*)(lds + WHOFF + off);
        blv[ni] = *(const bf16x8*)(lds + WLOFF + off);
    }
    #pragma unroll
    for (int mi = 0; mi < 4; ++mi) {
        bf16x8 ah = *(const bf16x8*)(lds + AOFF + (wm * 4 + mi) * 512 + lane * 8);
        #pragma unroll
        for (int ni = 0; ni < 4; ++ni) {
            acc[mi][ni] = __builtin_amdgcn_mfma_f32_16x16x32_bf16(ah, bhv[ni], acc[mi][ni], 0, 0, 0);
            acc[mi][ni] = __builtin_amdgcn_mfma_f32_16x16x32_bf16(ah, blv[ni], acc[mi][ni], 0, 0, 0);
        }
    }
    constexpr int ELDW = 68;
    float* S = (float*)lds + (size_t)w * 16 * ELDW;
    const int rrow = lane >> 3;
    const int grp  = lane & 7;
    #pragma unroll
    for (int mi = 0; mi < 4; ++mi) {
        __syncthreads();
        #pragma unroll
        for (int ni = 0; ni < 4; ++ni)
            #pragma unroll
            for (int reg = 0; reg < 4; ++reg)
                S[(lk * 4 + reg) * ELDW + ni * 16 + lr] = acc[mi][ni][reg];
        __syncthreads();
        #pragma unroll
        for (int it = 0; it < 2; ++it) {
            int row_i = rrow + it * 8;
            int gr = row0 + wm * 64 + mi * 16 + row_i;
            int gc = wn * 64 + grp * 8;
            if (gr >= NF) continue;
            float4 f0 = *(const float4*)(&S[row_i * ELDW + grp * 8]);
            float4 f1 = *(const float4*)(&S[row_i * ELDW + grp * 8 + 4]);
            float4 b0 = *(const float4*)(bfl + gc);
            float4 b1 = *(const float4*)(bfl + gc + 4);
            u16x8 hh;
            hh[0] = f2bf(fmaxf(f0.x + b0.x, 0.f));
            hh[1] = f2bf(fmaxf(f0.y + b0.y, 0.f));
            hh[2] = f2bf(fmaxf(f0.z + b0.z, 0.f));
            hh[3] = f2bf(fmaxf(f0.w + b0.w, 0.f));
            hh[4] = f2bf(fmaxf(f1.x + b1.x, 0.f));
            hh[5] = f2bf(fmaxf(f1.y + b1.y, 0.f));
            hh[6] = f2bf(fmaxf(f1.z + b1.z, 0.f));
            hh[7] = f2bf(fmaxf(f1.w + b1.w, 0.f));
            *(u16x8*)(hH + (size_t)gr * D + gc) = hh;
        }
    }
}

// ==== layer kernel: gemm tiles (+fused msg epilogue) + (MODE 0: agg) ========
// MODE 0: G = relu(A@root0^T + bias + msgs(ybuf)) for flight rows; plain
//         A@root0^T+bias for tail rows (finished by finish0). agg co-sched.
// MODE 1: fused readout — out[row] += sum(relu(A@root1^T+bias+msgs).Wout);
//         no G written at all.
template<int MODE>
__global__ __launch_bounds__(512) void layer_kernel(
    const ushort* __restrict__ A,
    const ushort* __restrict__ WtH, const ushort* __restrict__ WtL,
    const float* __restrict__ bias, ushort* __restrict__ G,
    const int* __restrict__ rp0, const int* __restrict__ csr0,
    const int* __restrict__ rp2, const int* __restrict__ csr2,
    float* __restrict__ agg,
    const float* __restrict__ ybuf,
    const int* __restrict__ rp1, const int* __restrict__ csr1, const float* __restrict__ inv1,
    const int* __restrict__ rp3, const int* __restrict__ csr3, const float* __restrict__ inv3,
    const float* __restrict__ wout, float* __restrict__ outp)
{
    constexpr int BM = 128, BK = 32;
    constexpr int PLANE = BM * BK;          // 4096 ushorts = 8 KB
    constexpr int BUF = 3 * PLANE;          // 12288 ushorts = 24 KB
    constexpr int LDW = 36;                 // fp32 epilogue scratch stride
    constexpr int nrows = (MODE == 0) ? NN : NF;
    constexpr int NT = (nrows + 127) / 128;   // row tiles
    constexpr int NG = NT * 2;
    constexpr int G8 = (NT / 8) * 16;         // full swizzle groups
    __shared__ __align__(16) ushort lds[2 * BUF];   // 49152 B
    const int t = threadIdx.x;
    const int b = blockIdx.x;
    if (MODE == 0 && b >= NG) {
        // ---- agg chunk
        int bb = b - NG;
        float* red = (float*)lds;        // 8 x 256 floats
        const int* rp; const int* csr; int dstn, chunk, nch; float* arow;
        if (bb < NA * 4) { dstn = bb >> 2; chunk = bb & 3; nch = 4;  rp = rp0; csr = csr0; arow = agg + (size_t)dstn * D; }
        else { int b2 = bb - NA * 4; dstn = b2 >> 6; chunk = b2 & 63; nch = 64; rp = rp2; csr = csr2; arow = agg + (size_t)(NA + dstn) * D; }
        int s = rp[dstn], e = rp[dstn + 1];
        int cnt = e - s;
        int lo = s + (int)((long long)cnt * chunk / nch);
        int hi = s + (int)((long long)cnt * (chunk + 1) / nch);
        int w8 = t >> 6, lane = t & 63;
        int span = hi - lo;
        int wlo = lo + (int)((long long)span * w8 / 8);
        int whi = lo + (int)((long long)span * (w8 + 1) / 8);
        int half = lane >> 5;
        int ch8 = (lane & 31) * 8;
        float acc[8] = {};
        int p = wlo;
        for (; p + 1 < whi; p += 2) {
            int r = csr[p + half];
            u16x8 v = *(const u16x8*)(A + (size_t)r * D + ch8);
            #pragma unroll
            for (int j = 0; j < 8; ++j) acc[j] += bf2f(v[j]);
        }
        if (p < whi && half == 0) {
            int r = csr[p];
            u16x8 v = *(const u16x8*)(A + (size_t)r * D + ch8);
            #pragma unroll
            for (int j = 0; j < 8; ++j) acc[j] += bf2f(v[j]);
        }
        #pragma unroll
        for (int j = 0; j < 8; ++j) acc[j] += __shfl_xor(acc[j], 32);
        if (lane < 32) {
            #pragma unroll
            for (int j = 0; j < 8; ++j) red[w8 * 256 + ch8 + j] = acc[j];
        }
        __syncthreads();
        if (t < 256) {
            float total = 0.f;
            #pragma unroll
            for (int j = 0; j < 8; ++j) total += red[j * 256 + t];
            atomicAdd(arow + t, total);
        }
        return;
    }
    // ---- gemm tile with XCD-pairing swizzle (bijective incl. tail) ----
    int rtile, ctile;
    if (b < G8) {
        int g = b >> 4, j = b & 15;
        rtile = g * 8 + (j & 7);
        ctile = j >> 3;
    } else {
        int j = b - G8;
        rtile = (NT / 8) * 8 + (j >> 1);
        ctile = j & 1;
    }
    const int row0 = rtile * BM;
    const int col0 = ctile * BM;
    const int w = t >> 6, lane = t & 63;    // 8 waves
    const int wm = w >> 2, wn = w & 3;      // 2x4 wave grid, 64x32 per wave
    const int lr = lane & 15;
    const int lk = lane >> 4;
    f32x4 acc[4][2] = {};

    const ushort* sp[3];
    int dofs[3];
    #pragma unroll
    for (int i = 0; i < 3; ++i) {
        int idx = w * 3 + i;
        int plane = idx >> 3, g = idx & 7;
        const ushort* base = (plane == 0) ? A : (plane == 1) ? WtH : WtL;
        int r = ((plane == 0) ? row0 : col0) + g * 16 + lr;
        if (plane == 0 && r >= nrows) r = nrows - 1;
        sp[i] = base + (size_t)r * D + lk * 8;
        dofs[i] = plane * PLANE + g * 512;
    }

    auto stage = [&](int kt, int buf) {
        ushort* bb2 = lds + buf * BUF;
        int k0 = kt * BK;
        #pragma unroll
        for (int i = 0; i < 3; ++i)
            gload_lds16(sp[i] + k0, bb2 + dofs[i]);
    };
    auto compute = [&](int buf) {
        const ushort* base = lds + buf * BUF;
        const ushort* As  = base;
        const ushort* WsH = base + PLANE;
        const ushort* WsL = base + 2 * PLANE;
        bf16x8 bh[2], bl[2];
        #pragma unroll
        for (int ni = 0; ni < 2; ++ni) {
            int off = (wn * 2 + ni) * 512 + lane * 8;
            bh[ni] = *(const bf16x8*)(&WsH[off]);
            bl[ni] = *(const bf16x8*)(&WsL[off]);
        }
        #pragma unroll
        for (int mi = 0; mi < 4; ++mi) {
            int off = (wm * 4 + mi) * 512 + lane * 8;
            bf16x8 ah = *(const bf16x8*)(&As[off]);
            #pragma unroll
            for (int ni = 0; ni < 2; ++ni) {
                acc[mi][ni] = __builtin_amdgcn_mfma_f32_16x16x32_bf16(ah, bh[ni], acc[mi][ni], 0, 0, 0);
                acc[mi][ni] = __builtin_amdgcn_mfma_f32_16x16x32_bf16(ah, bl[ni], acc[mi][ni], 0, 0, 0);
            }
        }
    };

    stage(0, 0);
    stage(1, 1);
#define PIPE_ITER(KT, PEND)                                        \
    asm volatile("s_waitcnt vmcnt(" #PEND ")" ::: "memory");       \
    __builtin_amdgcn_s_barrier();                                  \
    __builtin_amdgcn_sched_barrier(0);                             \
    compute((KT) & 1);                                             \
    __builtin_amdgcn_s_barrier();                                  \
    __builtin_amdgcn_sched_barrier(0);                             \
    if ((KT) + 2 < 8) stage((KT) + 2, (KT) & 1);
    PIPE_ITER(0, 3)
    PIPE_ITER(1, 3)
    PIPE_ITER(2, 3)
    PIPE_ITER(3, 3)
    PIPE_ITER(4, 3)
    PIPE_ITER(5, 3)
    PIPE_ITER(6, 3)
    PIPE_ITER(7, 0)
#undef PIPE_ITER

    __syncthreads();
    float* S = (float*)lds + (size_t)w * 16 * LDW;   // per-wave 16x36 fp32
    const int rrow = lane >> 2;            // 0..15 read-back row
    const int grp  = lane & 3;             // col octet (8 bf16)
    #pragma unroll
    for (int mi = 0; mi < 4; ++mi) {
        __syncthreads();
        #pragma unroll
        for (int ni = 0; ni < 2; ++ni)
            #pragma unroll
            for (int reg = 0; reg < 4; ++reg)
                S[(lk * 4 + reg) * LDW + ni * 16 + lr] = acc[mi][ni][reg];
        __syncthreads();
        int gr = row0 + wm * 64 + mi * 16 + rrow;
        int gc = col0 + wn * 32 + grp * 8;
        if (gr >= nrows) continue;
        float4 f0 = *(const float4*)(&S[rrow * LDW + grp * 8]);
        float4 f1 = *(const float4*)(&S[rrow * LDW + grp * 8 + 4]);
        float4 b0 = *(const float4*)(bias + gc);
        float4 b1 = *(const float4*)(bias + gc + 4);
        float v[8] = {f0.x + b0.x, f0.y + b0.y, f0.z + b0.z, f0.w + b0.w,
                      f1.x + b1.x, f1.y + b1.y, f1.z + b1.z, f1.w + b1.w};
        if (MODE == 0) {
            if (gr < NF) {
                float m[8] = {};
                int e0 = rp1[gr], e1 = rp1[gr + 1];
                for (int e = e0; e < e1; ++e) {
                    const float* yr = ybuf + (size_t)csr1[e] * D + gc;
                    float4 u0 = *(const float4*)yr;
                    float4 u1 = *(const float4*)(yr + 4);
                    m[0] += u0.x; m[1] += u0.y; m[2] += u0.z; m[3] += u0.w;
                    m[4] += u1.x; m[5] += u1.y; m[6] += u1.z; m[7] += u1.w;
                }
                float s1 = inv1[gr];
                #pragma unroll
                for (int j = 0; j < 8; ++j) { v[j] += s1 * m[j]; m[j] = 0.f; }
                e0 = rp3[gr]; e1 = rp3[gr + 1];
                for (int e = e0; e < e1; ++e) {
                    const float* yr = ybuf + (size_t)(NA + csr3[e]) * D + gc;
                    float4 u0 = *(const float4*)yr;
                    float4 u1 = *(const float4*)(yr + 4);
                    m[0] += u0.x; m[1] += u0.y; m[2] += u0.z; m[3] += u0.w;
                    m[4] += u1.x; m[5] += u1.y; m[6] += u1.z; m[7] += u1.w;
                }
                float s3 = inv3[gr];
                #pragma unroll
                for (int j = 0; j < 8; ++j) v[j] = fmaxf(v[j] + s3 * m[j], 0.f);
            }
            u16x8 hh;
            #pragma unroll
            for (int j = 0; j < 8; ++j) hh[j] = f2bf(v[j]);
            *(u16x8*)(G + (size_t)gr * D + gc) = hh;
        } else {
            // fused readout: relu(v + msgs) . wout, 4-lane reduce, atomic
            float m[8] = {};
            int e0 = rp1[gr], e1 = rp1[gr + 1];
            for (int e = e0; e < e1; ++e) {
                const float* yr = ybuf + (size_t)csr1[e] * D + gc;
                float4 u0 = *(const float4*)yr;
                float4 u1 = *(const float4*)(yr + 4);
                m[0] += u0.x; m[1] += u0.y; m[2] += u0.z; m[3] += u0.w;
                m[4] += u1.x; m[5] += u1.y; m[6] += u1.z; m[7] += u1.w;
            }
            float s1 = inv1[gr];
            #pragma unroll
            for (int j = 0; j < 8; ++j) { v[j] += s1 * m[j]; m[j] = 0.f; }
            e0 = rp3[gr]; e1 = rp3[gr + 1];
            for (int e = e0; e < e1; ++e) {
                const float* yr = ybuf + (size_t)(NA + csr3[e]) * D + gc;
                float4 u0 = *(const float4*)yr;
                float4 u1 = *(const float4*)(yr + 4);
                m[0] += u0.x; m[1] += u0.y; m[2] += u0.z; m[3] += u0.w;
                m[4] += u1.x; m[5] += u1.y; m[6] += u1.z; m[7] += u1.w;
            }
            float s3 = inv3[gr];
            float4 w0 = *(const float4*)(wout + gc);
            float4 w1 = *(const float4*)(wout + gc + 4);
            float wv[8] = {w0.x, w0.y, w0.z, w0.w, w1.x, w1.y, w1.z, w1.w};
            float pr = 0.f;
            #pragma unroll
            for (int j = 0; j < 8; ++j) pr += fmaxf(v[j] + s3 * m[j], 0.f) * wv[j];
            pr += __shfl_xor(pr, 1);
            pr += __shfl_xor(pr, 2);
            if (grp == 0) atomicAdd(outp + gr, pr);
        }
    }
}

// ==== finish0: smallT(+y1) for tail rows + out init, co-scheduled ===========
__global__ __launch_bounds__(256) void finish0_kernel(
    const float* __restrict__ agg, const float* __restrict__ wr0,
    const float* __restrict__ wr1,
    const float* __restrict__ inv0, const float* __restrict__ inv2,
    ushort* __restrict__ G, float* __restrict__ y1,
    float* __restrict__ outp, const float* __restrict__ bout)
{
    __shared__ float grow[256];
    const int b = blockIdx.x;
    const int t = threadIdx.x;
    if (b < NA + NC) {
        // smallT: G = relu(G + inv_deg*(agg @ Wr0[rel])) in place, then
        // y1[row] = Grow @ Wr1[rel] for layer-1 messages
        int row = b;
        int c = t;
        const float* a = agg + (size_t)row * D;
        const float* W = wr0 + (size_t)((row < NA) ? 0 : 2) * DD;
        float scale = (row < NA) ? inv0[row] : inv2[row - NA];
        float acc = 0.f;
        #pragma unroll 8
        for (int k = 0; k < D; ++k) acc += a[k] * W[k * D + c];
        size_t o = (size_t)(NF + row) * D + c;
        ushort hv = f2bf(fmaxf(bf2f(G[o]) + scale * acc, 0.f));
        G[o] = hv;
        grow[c] = bf2f(hv);
        __syncthreads();
        const float* W1 = wr1 + (size_t)((row < NA) ? 1 : 3) * DD;
        float acc2 = 0.f;
        #pragma unroll 8
        for (int k = 0; k < D; ++k) acc2 += grow[k] * W1[k * D + c];
        y1[(size_t)row * D + c] = acc2;
        return;
    }
    // out init: out[row] = bout[0] (layer-1 epilogue atomically accumulates)
    int idx = (b - (NA + NC)) * 256 + t;
    if (idx < NF) outp[idx] = bout[0];
}

extern "C" void kernel_launch(void* const* d_in, const int* in_sizes, int n_in,
                              void* d_out, int out_size, void* d_ws, size_t ws_size,
                              hipStream_t stream)
{
    const float* xf = (const float*)d_in[0];
    const float* xa = (const float*)d_in[1];
    const float* xc = (const float*)d_in[2];
    const float* Wf = (const float*)d_in[3];
    const float* bf = (const float*)d_in[4];
    const float* Wa = (const float*)d_in[5];
    const float* ba = (const float*)d_in[6];
    const float* Wc = (const float*)d_in[7];
    const float* bc = (const float*)d_in[8];
    const float* basis0 = (const float*)d_in[9];
    const float* comp0  = (const float*)d_in[10];
    const float* root0  = (const float*)d_in[11];
    const float* bias0  = (const float*)d_in[12];
    const float* basis1 = (const float*)d_in[13];
    const float* comp1  = (const float*)d_in[14];
    const float* root1  = (const float*)d_in[15];
    const float* bias1  = (const float*)d_in[16];
    const float* Wout = (const float*)d_in[17];
    const float* bout = (const float*)d_in[18];
    const int* src0 = (const int*)d_in[19];
    const int* dst0 = (const int*)d_in[20];
    const int* src1 = (const int*)d_in[21];
    const int* dst1 = (const int*)d_in[22];
    const int* src2 = (const int*)d_in[23];
    const int* dst2 = (const int*)d_in[24];
    const int* src3 = (const int*)d_in[25];
    const int* dst3 = (const int*)d_in[26];
    float* out = (float*)d_out;

    char* ws = (char*)d_ws;
    size_t off = 0;
    auto alloc = [&](size_t bytes) -> char* {
        char* p = ws + off;
        off = (off + bytes + 255) & ~(size_t)255;
        return p;
    };
    ushort* hH  = (ushort*)alloc((size_t)NN * D * 2);
    ushort* gH  = (ushort*)alloc((size_t)NN * D * 2);
    ushort* WtH0 = (ushort*)alloc((size_t)DD * 2);
    ushort* WtL0 = (ushort*)alloc((size_t)DD * 2);
    ushort* WtH1 = (ushort*)alloc((size_t)DD * 2);
    ushort* WtL1 = (ushort*)alloc((size_t)DD * 2);
    ushort* WfTH = (ushort*)alloc((size_t)D * 32 * 2);
    ushort* WfTL = (ushort*)alloc((size_t)D * 32 * 2);
    float* wr0    = (float*)alloc((size_t)4 * DD * 4);
    float* wr1    = (float*)alloc((size_t)4 * DD * 4);
    float* ybuf   = (float*)alloc((size_t)(NA + NC) * D * 4);
    float* aggbuf = (float*)alloc((size_t)(NA + NC) * D * 4);
    int*   deg13  = (int*)  alloc((size_t)2 * NF * 4);
    int* deg1 = deg13; int* deg3 = deg13 + NF;
    float* inv1 = (float*)alloc((size_t)NF * 4);
    float* inv3 = (float*)alloc((size_t)NF * 4);
    float* inv0 = (float*)alloc((size_t)NA * 4);
    float* inv2 = (float*)alloc((size_t)NC * 4);
    int* rp0 = (int*)alloc((NA + 1) * 4);
    int* rp1 = (int*)alloc((size_t)(NF + 1) * 4);
    int* rp2 = (int*)alloc((NC + 1) * 4);
    int* rp3 = (int*)alloc((size_t)(NF + 1) * 4);
    int* cu1 = (int*)alloc((size_t)(NF + 1) * 4);
    int* cu3 = (int*)alloc((size_t)(NF + 1) * 4);
    int* csr0 = (int*)alloc((size_t)E * 4);
    int* csr1 = (int*)alloc((size_t)E * 4);
    int* csr2 = (int*)alloc((size_t)E * 4);
    int* csr3 = (int*)alloc((size_t)E * 4);
    int* bsum = (int*)alloc(256 * 4);
    int* bh0  = (int*)alloc((size_t)NSL * NA * 4);
    int* bh2  = (int*)alloc((size_t)NSL * NC * 4);
    (void)ws_size; (void)in_sizes; (void)n_in; (void)out_size;

    // deg13 must be zero before prep_kernel's deg_count blocks (stream order)
    hipMemsetAsync(deg13, 0, (size_t)2 * NF * 4, stream);

    // K1: hist02 + deg_count + wsplit(x2) + wr(x2)
    prep_kernel<<<K1_WR1_END, 256, 0, stream>>>(
        dst0, dst2, bh0, bh2, aggbuf, Wf, WfTH, WfTL,
        dst1, dst3, deg1, deg3,
        root0, WtH0, WtL0, root1, WtH1, WtL1,
        basis0, comp0, wr0, basis1, comp1, wr1);

    // K2: scanA + scan02
    scan_kernel<<<197, 1024, 0, stream>>>(
        deg1, deg3, bsum, bh0, bh2, rp0, rp2, inv0, inv2);

    // scanC (standalone: produces cu1/cu3 for fill13)
    scanC_kernel<<<196, 1024, 0, stream>>>(
        deg1, deg3, bsum, rp1, rp3, cu1, cu3, inv1, inv3);

    // work: encoder + tail(+y0) + csr_fill13 + fill02, all co-scheduled
    work_kernel<<<W_TOTAL, 512, 0, stream>>>(
        xf, WfTH, WfTL, bf, xa, Wa, ba, xc, Wc, bc, hH,
        src1, dst1, src3, dst3, cu1, cu3, csr1, csr3,
        src0, dst0, src2, dst2, bh0, bh2, csr0, csr2,
        wr0, ybuf);

    // ---- layer 0: {gemm(+fused msg_relu) + agg} co-scheduled
    constexpr int NG0 = ((NN + 127) / 128) * 2;
    layer_kernel<0><<<NG0 + AGGB, 512, 0, stream>>>(
        hH, WtH0, WtL0, bias0, gH,
        rp0, csr0, rp2, csr2, aggbuf,
        ybuf, rp1, csr1, inv1, rp3, csr3, inv3,
        nullptr, nullptr);

    // finish0: smallT(+y1) for 430 tail rows + out init
    constexpr int OUTB = (NF + 255) / 256;
    finish0_kernel<<<(NA + NC) + OUTB, 256, 0, stream>>>(
        aggbuf, wr0, wr1, inv0, inv2, gH, ybuf, out, bout);

    // ---- layer 1: gemm with fused msg+readout epilogue (no G2 in memory)
    constexpr int NG1 = ((NF + 127) / 128) * 2;
    layer_kernel<1><<<NG1, 512, 0, stream>>>(
        gH, WtH1, WtL1, bias1, nullptr,
        nullptr, nullptr, nullptr, nullptr, nullptr,
        ybuf, rp1, csr1, inv1, rp3, csr3, inv3,
        Wout, out);
}

// Round 27
// 325.800 us; speedup vs baseline: 1.1935x; 1.1935x over previous
//
#include <hip/hip_runtime.h>
#include <hip/hip_bf16.h>
#include <cstdint>
#include <cstddef>

constexpr int NF = 100000;
constexpr int NA = 400;
constexpr int NC = 30;
constexpr int NN = NF + NA + NC;     // 100430
constexpr int D  = 256;
constexpr int DD = D * D;            // 65536
constexpr int E  = 250000;
constexpr int NSL = 128;             // slices for r0/r2 counting sort
constexpr int FBLK = (NF + 127) / 128;   // 782 flight-encoder blocks
constexpr int TAILB = (NA + NC + 7) / 8; // 54 scalar-tail blocks
constexpr int F13B = (2 * E + 511) / 512; // 977 csr_fill13 blocks (512 thr)
constexpr int AGGB = NA * 4 + NC * 64;    // 3520 agg chunks
constexpr int YB   = (NA + NC) / 2;       // 215 y blocks (2 rows each)

// K1 block ranges
constexpr int K1_HIST_END = 2 * NSL;                       // 256
constexpr int K1_DEG_END  = K1_HIST_END + (2 * E + 255) / 256;  // 2210
constexpr int K1_WS0_END  = K1_DEG_END + 256;              // 2466
constexpr int K1_WS1_END  = K1_WS0_END + 256;              // 2722
constexpr int K1_WR0_END  = K1_WS1_END + 1024;             // 3746
constexpr int K1_WR1_END  = K1_WR0_END + 1024;             // 4770

// work_kernel block ranges: encoder | tail | fill13 | fill02
constexpr int W_ENC_END  = FBLK;                 // 782
constexpr int W_TAIL_END = W_ENC_END + TAILB;    // 836
constexpr int W_F13_END  = W_TAIL_END + F13B;    // 1813
constexpr int W_TOTAL    = W_F13_END + 2 * NSL;  // 2069

typedef __attribute__((ext_vector_type(8))) short bf16x8;
typedef __attribute__((ext_vector_type(4))) float f32x4;
typedef __attribute__((ext_vector_type(8))) ushort u16x8;

__device__ inline ushort f2bf(float f) {
    __hip_bfloat16 h = __float2bfloat16(f);
    return __builtin_bit_cast(ushort, h);
}
__device__ inline float bf2f(ushort u) {
    __hip_bfloat16 h = __builtin_bit_cast(__hip_bfloat16, u);
    return __bfloat162float(h);
}

// async global->LDS, 16B per lane: LDS dest = base + lane*16 (wave-linear)
__device__ inline void gload_lds16(const ushort* g, ushort* l) {
    __builtin_amdgcn_global_load_lds(
        (const __attribute__((address_space(1))) void*)g,
        (__attribute__((address_space(3))) void*)l, 16, 0, 0);
}

// ==== K1: hist02 + deg_count + wsplit(x2) + wr(x2), co-scheduled ============
__global__ __launch_bounds__(256) void prep_kernel(
    const int* __restrict__ dst0, const int* __restrict__ dst2,
    int* __restrict__ bh0, int* __restrict__ bh2,
    float* __restrict__ aggz,
    const float* __restrict__ Wf, ushort* __restrict__ WfTH, ushort* __restrict__ WfTL,
    const int* __restrict__ dst1, const int* __restrict__ dst3,
    int* __restrict__ deg1, int* __restrict__ deg3,
    const float* __restrict__ root0, ushort* __restrict__ WtH0, ushort* __restrict__ WtL0,
    const float* __restrict__ root1, ushort* __restrict__ WtH1, ushort* __restrict__ WtL1,
    const float* __restrict__ basis0, const float* __restrict__ comp0, float* __restrict__ wr0,
    const float* __restrict__ basis1, const float* __restrict__ comp1, float* __restrict__ wr1)
{
    __shared__ int hist[NA];
    const int b = blockIdx.x;
    const int t = threadIdx.x;
    if (b < K1_HIST_END) {
        for (int i = b * 256 + t; i < (NA + NC) * D; i += K1_HIST_END * 256)
            aggz[i] = 0.f;
        if (b < 32) {
            float wv = Wf[(size_t)b * D + t];
            ushort hi = f2bf(wv);
            WfTH[(size_t)t * 32 + b] = hi;
            WfTL[(size_t)t * 32 + b] = f2bf(wv - bf2f(hi));
        }
        bool isR2 = (b >= NSL);
        int sl = isR2 ? b - NSL : b;
        const int* dst = isR2 ? dst2 : dst0;
        int nb = isR2 ? NC : NA;
        for (int i = t; i < nb; i += 256) hist[i] = 0;
        __syncthreads();
        int lo = (int)((long long)E * sl / NSL);
        int hi = (int)((long long)E * (sl + 1) / NSL);
        for (int e = lo + t; e < hi; e += 256)
            atomicAdd(&hist[dst[e]], 1);
        __syncthreads();
        int* bh = isR2 ? (bh2 + sl * NC) : (bh0 + sl * NA);
        for (int i = t; i < nb; i += 256) bh[i] = hist[i];
    } else if (b < K1_DEG_END) {
        int idx = (b - K1_HIST_END) * 256 + t;
        if (idx < 2 * E) {
            if (idx < E) atomicAdd(&deg1[dst1[idx]], 1);
            else         atomicAdd(&deg3[dst3[idx - E]], 1);
        }
    } else if (b < K1_WS0_END) {
        int n = b - K1_DEG_END;
        float w = root0[(size_t)t * D + n];
        ushort hi = f2bf(w);
        WtH0[(size_t)n * D + t] = hi;
        WtL0[(size_t)n * D + t] = f2bf(w - bf2f(hi));
    } else if (b < K1_WS1_END) {
        int n = b - K1_WS0_END;
        float w = root1[(size_t)t * D + n];
        ushort hi = f2bf(w);
        WtH1[(size_t)n * D + t] = hi;
        WtL1[(size_t)n * D + t] = f2bf(w - bf2f(hi));
    } else if (b < K1_WR0_END) {
        int idx = (b - K1_WS1_END) * 256 + t;
        int r = idx >> 16;
        int io = idx & (DD - 1);
        wr0[idx] = comp0[r * 3 + 0] * basis0[io]
                 + comp0[r * 3 + 1] * basis0[DD + io]
                 + comp0[r * 3 + 2] * basis0[2 * DD + io];
    } else {
        int idx = (b - K1_WR0_END) * 256 + t;
        int r = idx >> 16;
        int io = idx & (DD - 1);
        wr1[idx] = comp1[r * 3 + 0] * basis1[io]
                 + comp1[r * 3 + 1] * basis1[DD + io]
                 + comp1[r * 3 + 2] * basis1[2 * DD + io];
    }
}

// ==== K2: scanA (blocks 0..195) + scan02 (block 196), co-scheduled ==========
__global__ __launch_bounds__(1024) void scan_kernel(
    const int* __restrict__ deg1, const int* __restrict__ deg3,
    int* __restrict__ bsum,
    int* __restrict__ bh0, int* __restrict__ bh2,
    int* __restrict__ rp0, int* __restrict__ rp2,
    float* __restrict__ inv0, float* __restrict__ inv2)
{
    __shared__ int s[1024];
    __shared__ int tot[512];
    __shared__ int exc[512];
    const int b = blockIdx.x;
    const int t = threadIdx.x;
    if (b < 196) {
        bool isR3 = (b >= 98);
        const int* deg = isR3 ? deg3 : deg1;
        int chunk = isR3 ? b - 98 : b;
        int i = chunk * 1024 + t;
        int v = (i < NF) ? deg[i] : 0;
        s[t] = v;
        __syncthreads();
        for (int ofs = 512; ofs > 0; ofs >>= 1) {
            if (t < ofs) s[t] += s[t + ofs];
            __syncthreads();
        }
        if (t == 0) bsum[(isR3 ? 128 : 0) + chunk] = s[0];
        return;
    }
    int cnt = 0;
    if (t < NA) {
        int ss = 0;
        for (int sl = 0; sl < NSL; ++sl) {
            int v = bh0[sl * NA + t]; bh0[sl * NA + t] = ss; ss += v;
        }
        cnt = ss;
    } else if (t < NA + NC) {
        int bin = t - NA; int ss = 0;
        for (int sl = 0; sl < NSL; ++sl) {
            int v = bh2[sl * NC + bin]; bh2[sl * NC + bin] = ss; ss += v;
        }
        cnt = ss;
    }
    if (t < 512) tot[t] = cnt;
    __syncthreads();
    for (int ofs = 1; ofs < 512; ofs <<= 1) {
        int v = 0;
        if (t < 512 && t >= ofs) v = tot[t - ofs];
        __syncthreads();
        if (t < 512) tot[t] += v;
        __syncthreads();
    }
    if (t < 512) {
        int ex = tot[t] - cnt;
        if (t < NA) {
            exc[t] = ex;
            rp0[t] = ex;
            inv0[t] = 1.0f / (float)(cnt > 1 ? cnt : 1);
            if (t == 0) { rp0[NA] = E; rp2[NC] = E; }
        } else if (t < NA + NC) {
            exc[t] = ex - E;
            rp2[t - NA] = ex - E;
            inv2[t - NA] = 1.0f / (float)(cnt > 1 ? cnt : 1);
        } else exc[t] = 0;
    }
    __syncthreads();
    for (int idx = t; idx < NSL * NA; idx += 1024) {
        int sl = idx / NA; int bin = idx - sl * NA;
        bh0[idx] += exc[bin];
    }
    for (int idx = t; idx < NSL * NC; idx += 1024) {
        int sl = idx / NC; int bin = idx - sl * NC;
        bh2[idx] += exc[NA + bin];
    }
}

// ==== scanC (with inlined scanB), standalone -------------------------------
__global__ __launch_bounds__(1024) void scanC_kernel(
    const int* __restrict__ deg1, const int* __restrict__ deg3,
    const int* __restrict__ bsum,
    int* __restrict__ rp1, int* __restrict__ rp3,
    int* __restrict__ cu1, int* __restrict__ cu3,
    float* __restrict__ inv1, float* __restrict__ inv3)
{
    __shared__ int s[1024];
    __shared__ int s2[256];
    int t = threadIdx.x;
    int b = blockIdx.x;                    // 0..195
    int vb = 0;
    if (t < 256) {
        vb = ((t & 127) < 98) ? bsum[t] : 0;
        s2[t] = vb;
    }
    __syncthreads();
    for (int ofs = 1; ofs < 128; ofs <<= 1) {
        int a = 0;
        if (t < 256 && (t & 127) >= ofs) a = s2[t - ofs];
        __syncthreads();
        if (t < 256) s2[t] += a;
        __syncthreads();
    }
    if (t < 256) s2[t] -= vb;          // exclusive
    __syncthreads();
    const int* deg; int* rp; int* cu; float* inv; int chunk; int prefix;
    if (b < 98) { deg = deg1; rp = rp1; cu = cu1; inv = inv1; chunk = b;      prefix = s2[chunk]; }
    else        { deg = deg3; rp = rp3; cu = cu3; inv = inv3; chunk = b - 98; prefix = s2[128 + chunk]; }
    int i = chunk * 1024 + t;
    int v = (i < NF) ? deg[i] : 0;
    s[t] = v;
    __syncthreads();
    for (int ofs = 1; ofs < 1024; ofs <<= 1) {
        int a = (t >= ofs) ? s[t - ofs] : 0;
        __syncthreads();
        s[t] += a;
        __syncthreads();
    }
    int ex = prefix + s[t] - v;
    if (i < NF) {
        rp[i] = ex;
        cu[i] = ex;
        inv[i] = 1.0f / (float)(v > 1 ? v : 1);
    }
    if (i == 0) rp[NF] = E;
}

// ==== work_kernel: encoder + tail + csr_fill13 + fill02, co-scheduled =======
__global__ __launch_bounds__(512) void work_kernel(
    const float* __restrict__ xf,
    const ushort* __restrict__ WtH8, const ushort* __restrict__ WtL8,
    const float* __restrict__ bfl,
    const float* __restrict__ xa, const float* __restrict__ Wa, const float* __restrict__ ba,
    const float* __restrict__ xc, const float* __restrict__ Wc, const float* __restrict__ bc,
    ushort* __restrict__ hH,
    const int* __restrict__ src1, const int* __restrict__ dst1,
    const int* __restrict__ src3, const int* __restrict__ dst3,
    int* __restrict__ cu1, int* __restrict__ cu3,
    int* __restrict__ csr1, int* __restrict__ csr3,
    const int* __restrict__ src0, const int* __restrict__ dst0,
    const int* __restrict__ src2, const int* __restrict__ dst2,
    const int* __restrict__ bh0, const int* __restrict__ bh2,
    int* __restrict__ csr0, int* __restrict__ csr2)
{
    __shared__ __align__(16) ushort lds[20480];            // 40960 B
    const int t = threadIdx.x;
    const int b = blockIdx.x;
    if (b >= W_F13_END) {
        // ---- fill02 (512 threads, LDS cursor)
        int bb = b - W_F13_END;
        int* cur = (int*)lds;
        bool isR2 = (bb >= NSL);
        int sl = isR2 ? bb - NSL : bb;
        const int* src = isR2 ? src2 : src0;
        const int* dst = isR2 ? dst2 : dst0;
        const int* bh  = isR2 ? (bh2 + sl * NC) : (bh0 + sl * NA);
        int* csr       = isR2 ? csr2 : csr0;
        int nb = isR2 ? NC : NA;
        for (int i = t; i < nb; i += 512) cur[i] = bh[i];
        __syncthreads();
        int lo = (int)((long long)E * sl / NSL);
        int hi = (int)((long long)E * (sl + 1) / NSL);
        for (int e = lo + t; e < hi; e += 512) {
            int pos = atomicAdd(&cur[dst[e]], 1);
            csr[pos] = src[e];
        }
        return;
    }
    if (b >= W_TAIL_END) {
        // ---- csr_fill13
        int idx = (b - W_TAIL_END) * 512 + t;
        if (idx < 2 * E) {
            if (idx < E) {
                int pos = atomicAdd(&cu1[dst1[idx]], 1);
                csr1[pos] = src1[idx];
            } else {
                int e = idx - E;
                int pos = atomicAdd(&cu3[dst3[e]], 1);
                csr3[pos] = src3[e];
            }
        }
        return;
    }
    if (b >= W_ENC_END) {
        // ---- airports + carriers scalar path
        int c = t & 255;
        int i0 = t >> 8;
        int base = (b - W_ENC_END) * 8;
        for (int i = i0; i < 8; i += 2) {
            int row = base + i;
            if (row >= NA + NC) break;
            float acc;
            if (row < NA) {
                const float* xr = xa + (size_t)row * 16;
                acc = ba[c];
                #pragma unroll
                for (int k = 0; k < 16; ++k) acc += xr[k] * Wa[k * D + c];
            } else {
                const float* xr = xc + (size_t)(row - NA) * 8;
                acc = bc[c];
                #pragma unroll
                for (int k = 0; k < 8; ++k) acc += xr[k] * Wc[k * D + c];
            }
            hH[(size_t)(NF + row) * D + c] = f2bf(fmaxf(acc, 0.f));
        }
        return;
    }
    // ---- flight MFMA encoder
    constexpr int AOFF = 0, WHOFF = 4096, WLOFF = 12288;   // ushort offsets
    const int row0 = b * 128;
    const int w = t >> 6, lane = t & 63;     // 8 waves
    const int wm = w >> 2, wn = w & 3;       // 2x4 grid, 64 rows x 64 cols/wave
    const int lr = lane & 15;
    const int lk = lane >> 4;
    {
        int r = t >> 2;                      // 0..127
        int seg = (t & 3) * 8;               // 0,8,16,24
        int gr = row0 + r; if (gr >= NF) gr = NF - 1;
        const float* xr = xf + (size_t)gr * 32 + seg;
        float4 a0 = *(const float4*)xr;
        float4 a1 = *(const float4*)(xr + 4);
        u16x8 bb;
        bb[0] = f2bf(a0.x); bb[1] = f2bf(a0.y); bb[2] = f2bf(a0.z); bb[3] = f2bf(a0.w);
        bb[4] = f2bf(a1.x); bb[5] = f2bf(a1.y); bb[6] = f2bf(a1.z); bb[7] = f2bf(a1.w);
        int g = r >> 4, rr = r & 15, kg = seg >> 3;
        *(u16x8*)(lds + AOFF + g * 512 + (rr + 16 * kg) * 8) = bb;
    }
    #pragma unroll
    for (int i = 0; i < 4; ++i) {
        int u = w * 4 + i;                   // 0..31
        int plane = u >> 4, g = u & 15;
        const ushort* src = (plane ? WtL8 : WtH8) + ((size_t)(g * 16 + lr)) * 32 + lk * 8;
        ushort* dst = lds + (plane ? WLOFF : WHOFF) + g * 512;
        gload_lds16(src, dst);
    }
    __syncthreads();
    f32x4 acc[4][4] = {};
    bf16x8 bhv[4], blv[4];
    #pragma unroll
    for (int ni = 0; ni < 4; ++ni) {
        int off = (wn * 4 + ni) * 512 + lane * 8;
        bhv[ni] = *(const bf16x8*)(lds + WHOFF + off);
        blv[ni] = *(const bf16x8*)(lds + WLOFF + off);
    }
    #pragma unroll
    for (int mi = 0; mi < 4; ++mi) {
        bf16x8 ah = *(const bf16x8*)(lds + AOFF + (wm * 4 + mi) * 512 + lane * 8);
        #pragma unroll
        for (int ni = 0; ni < 4; ++ni) {
            acc[mi][ni] = __builtin_amdgcn_mfma_f32_16x16x32_bf16(ah, bhv[ni], acc[mi][ni], 0, 0, 0);
            acc[mi][ni] = __builtin_amdgcn_mfma_f32_16x16x32_bf16(ah, blv[ni], acc[mi][ni], 0, 0, 0);
        }
    }
    constexpr int ELDW = 68;
    float* S = (float*)lds + (size_t)w * 16 * ELDW;
    const int rrow = lane >> 3;
    const int grp  = lane & 7;
    #pragma unroll
    for (int mi = 0; mi < 4; ++mi) {
        __syncthreads();
        #pragma unroll
        for (int ni = 0; ni < 4; ++ni)
            #pragma unroll
            for (int reg = 0; reg < 4; ++reg)
                S[(lk * 4 + reg) * ELDW + ni * 16 + lr] = acc[mi][ni][reg];
        __syncthreads();
        #pragma unroll
        for (int it = 0; it < 2; ++it) {
            int row_i = rrow + it * 8;
            int gr = row0 + wm * 64 + mi * 16 + row_i;
            int gc = wn * 64 + grp * 8;
            if (gr >= NF) continue;
            float4 f0 = *(const float4*)(&S[row_i * ELDW + grp * 8]);
            float4 f1 = *(const float4*)(&S[row_i * ELDW + grp * 8 + 4]);
            float4 b0 = *(const float4*)(bfl + gc);
            float4 b1 = *(const float4*)(bfl + gc + 4);
            u16x8 hh;
            hh[0] = f2bf(fmaxf(f0.x + b0.x, 0.f));
            hh[1] = f2bf(fmaxf(f0.y + b0.y, 0.f));
            hh[2] = f2bf(fmaxf(f0.z + b0.z, 0.f));
            hh[3] = f2bf(fmaxf(f0.w + b0.w, 0.f));
            hh[4] = f2bf(fmaxf(f1.x + b1.x, 0.f));
            hh[5] = f2bf(fmaxf(f1.y + b1.y, 0.f));
            hh[6] = f2bf(fmaxf(f1.z + b1.z, 0.f));
            hh[7] = f2bf(fmaxf(f1.w + b1.w, 0.f));
            *(u16x8*)(hH + (size_t)gr * D + gc) = hh;
        }
    }
}

// ==== layer kernel: gemm tiles + (MODE 0: agg chunks) + y rows, co-sched ====
// gemm block decode uses an XCD-pairing swizzle: the two column tiles of one
// row tile get blockIdx values differing by exactly 8 (same XCD under
// round-robin dispatch) so the shared 64 KB A panel is an L2 hit on reuse.
template<int MODE>
__global__ __launch_bounds__(512) void layer_kernel(
    const ushort* __restrict__ A,
    const ushort* __restrict__ WtH, const ushort* __restrict__ WtL,
    const float* __restrict__ bias, ushort* __restrict__ G,
    const float* __restrict__ wr, float* __restrict__ y,
    const int* __restrict__ rp0, const int* __restrict__ csr0,
    const int* __restrict__ rp2, const int* __restrict__ csr2,
    float* __restrict__ agg)
{
    constexpr int BM = 128, BK = 32;
    constexpr int PLANE = BM * BK;          // 4096 ushorts = 8 KB
    constexpr int BUF = 3 * PLANE;          // 12288 ushorts = 24 KB
    constexpr int LDW = 36;                 // fp32 epilogue scratch stride
    constexpr int nrows = (MODE == 0) ? NN : NF;
    constexpr int NT = (nrows + 127) / 128;   // row tiles
    constexpr int NG = NT * 2;
    constexpr int G8 = (NT / 8) * 16;         // full swizzle groups
    constexpr int NAGG = (MODE == 0) ? AGGB : 0;
    __shared__ __align__(16) ushort lds[2 * BUF];   // 49152 B
    const int t = threadIdx.x;
    const int b = blockIdx.x;
    if (b >= NG) {
        int bb = b - NG;
        if (MODE == 0 && bb < NAGG) {
            float* red = (float*)lds;        // 8 x 256 floats
            const int* rp; const int* csr; int dstn, chunk, nch; float* arow;
            if (bb < NA * 4) { dstn = bb >> 2; chunk = bb & 3; nch = 4;  rp = rp0; csr = csr0; arow = agg + (size_t)dstn * D; }
            else { int b2 = bb - NA * 4; dstn = b2 >> 6; chunk = b2 & 63; nch = 64; rp = rp2; csr = csr2; arow = agg + (size_t)(NA + dstn) * D; }
            int s = rp[dstn], e = rp[dstn + 1];
            int cnt = e - s;
            int lo = s + (int)((long long)cnt * chunk / nch);
            int hi = s + (int)((long long)cnt * (chunk + 1) / nch);
            int w8 = t >> 6, lane = t & 63;
            int span = hi - lo;
            int wlo = lo + (int)((long long)span * w8 / 8);
            int whi = lo + (int)((long long)span * (w8 + 1) / 8);
            int half = lane >> 5;
            int ch8 = (lane & 31) * 8;
            float acc[8] = {};
            int p = wlo;
            for (; p + 1 < whi; p += 2) {
                int r = csr[p + half];
                u16x8 v = *(const u16x8*)(A + (size_t)r * D + ch8);
                #pragma unroll
                for (int j = 0; j < 8; ++j) acc[j] += bf2f(v[j]);
            }
            if (p < whi && half == 0) {
                int r = csr[p];
                u16x8 v = *(const u16x8*)(A + (size_t)r * D + ch8);
                #pragma unroll
                for (int j = 0; j < 8; ++j) acc[j] += bf2f(v[j]);
            }
            #pragma unroll
            for (int j = 0; j < 8; ++j) acc[j] += __shfl_xor(acc[j], 32);
            if (lane < 32) {
                #pragma unroll
                for (int j = 0; j < 8; ++j) red[w8 * 256 + ch8 + j] = acc[j];
            }
            __syncthreads();
            if (t < 256) {
                float total = 0.f;
                #pragma unroll
                for (int j = 0; j < 8; ++j) total += red[j * 256 + t];
                atomicAdd(arow + t, total);
            }
            return;
        }
        int yb = bb - NAGG;
        int row = yb * 2 + (t >> 8);
        if (row < NA + NC) {
            int c = t & 255;
            const ushort* sH = A + (size_t)(NF + row) * D;
            const float* W = wr + (size_t)((row < NA) ? 1 : 3) * DD;
            float acc = 0.f;
            #pragma unroll 8
            for (int k = 0; k < D; ++k) acc += bf2f(sH[k]) * W[k * D + c];
            y[(size_t)row * D + c] = acc;
        }
        return;
    }
    // ---- gemm tile with XCD-pairing swizzle (bijective incl. tail) ----
    int rtile, ctile;
    if (b < G8) {
        int g = b >> 4, j = b & 15;
        rtile = g * 8 + (j & 7);
        ctile = j >> 3;
    } else {
        int j = b - G8;
        rtile = (NT / 8) * 8 + (j >> 1);
        ctile = j & 1;
    }
    const int row0 = rtile * BM;
    const int col0 = ctile * BM;
    const int w = t >> 6, lane = t & 63;    // 8 waves
    const int wm = w >> 2, wn = w & 3;      // 2x4 wave grid, 64x32 per wave
    const int lr = lane & 15;
    const int lk = lane >> 4;
    f32x4 acc[4][2] = {};

    const ushort* sp[3];
    int dofs[3];
    #pragma unroll
    for (int i = 0; i < 3; ++i) {
        int idx = w * 3 + i;
        int plane = idx >> 3, g = idx & 7;
        const ushort* base = (plane == 0) ? A : (plane == 1) ? WtH : WtL;
        int r = ((plane == 0) ? row0 : col0) + g * 16 + lr;
        if (plane == 0 && r >= nrows) r = nrows - 1;
        sp[i] = base + (size_t)r * D + lk * 8;
        dofs[i] = plane * PLANE + g * 512;
    }

    auto stage = [&](int kt, int buf) {
        ushort* bb2 = lds + buf * BUF;
        int k0 = kt * BK;
        #pragma unroll
        for (int i = 0; i < 3; ++i)
            gload_lds16(sp[i] + k0, bb2 + dofs[i]);
    };
    auto compute = [&](int buf) {
        const ushort* base = lds + buf * BUF;
        const ushort* As  = base;
        const ushort* WsH = base + PLANE;
        const ushort* WsL = base + 2 * PLANE;
        bf16x8 bh[2], bl[2];
        #pragma unroll
        for (int ni = 0; ni < 2; ++ni) {
            int off = (wn * 2 + ni) * 512 + lane * 8;
            bh[ni] = *(const bf16x8*)(&WsH[off]);
            bl[ni] = *(const bf16x8*)(&WsL[off]);
        }
        #pragma unroll
        for (int mi = 0; mi < 4; ++mi) {
            int off = (wm * 4 + mi) * 512 + lane * 8;
            bf16x8 ah = *(const bf16x8*)(&As[off]);
            #pragma unroll
            for (int ni = 0; ni < 2; ++ni) {
                acc[mi][ni] = __builtin_amdgcn_mfma_f32_16x16x32_bf16(ah, bh[ni], acc[mi][ni], 0, 0, 0);
                acc[mi][ni] = __builtin_amdgcn_mfma_f32_16x16x32_bf16(ah, bl[ni], acc[mi][ni], 0, 0, 0);
            }
        }
    };

    stage(0, 0);
    stage(1, 1);
#define PIPE_ITER(KT, PEND)                                        \
    asm volatile("s_waitcnt vmcnt(" #PEND ")" ::: "memory");       \
    __builtin_amdgcn_s_barrier();                                  \
    __builtin_amdgcn_sched_barrier(0);                             \
    compute((KT) & 1);                                             \
    __builtin_amdgcn_s_barrier();                                  \
    __builtin_amdgcn_sched_barrier(0);                             \
    if ((KT) + 2 < 8) stage((KT) + 2, (KT) & 1);
    PIPE_ITER(0, 3)
    PIPE_ITER(1, 3)
    PIPE_ITER(2, 3)
    PIPE_ITER(3, 3)
    PIPE_ITER(4, 3)
    PIPE_ITER(5, 3)
    PIPE_ITER(6, 3)
    PIPE_ITER(7, 0)
#undef PIPE_ITER

    __syncthreads();
    float* S = (float*)lds + (size_t)w * 16 * LDW;   // per-wave 16x36 fp32
    const int rrow = lane >> 2;            // 0..15 read-back row
    const int grp  = lane & 3;             // col octet (8 bf16)
    #pragma unroll
    for (int mi = 0; mi < 4; ++mi) {
        __syncthreads();
        #pragma unroll
        for (int ni = 0; ni < 2; ++ni)
            #pragma unroll
            for (int reg = 0; reg < 4; ++reg)
                S[(lk * 4 + reg) * LDW + ni * 16 + lr] = acc[mi][ni][reg];
        __syncthreads();
        int gr = row0 + wm * 64 + mi * 16 + rrow;
        int gc = col0 + wn * 32 + grp * 8;
        if (gr >= nrows) continue;
        float4 f0 = *(const float4*)(&S[rrow * LDW + grp * 8]);
        float4 f1 = *(const float4*)(&S[rrow * LDW + grp * 8 + 4]);
        float4 b0 = *(const float4*)(bias + gc);
        float4 b1 = *(const float4*)(bias + gc + 4);
        float v[8] = {f0.x + b0.x, f0.y + b0.y, f0.z + b0.z, f0.w + b0.w,
                      f1.x + b1.x, f1.y + b1.y, f1.z + b1.z, f1.w + b1.w};
        u16x8 hh;
        #pragma unroll
        for (int j = 0; j < 8; ++j) hh[j] = f2bf(v[j]);
        *(u16x8*)(G + (size_t)gr * D + gc) = hh;
    }
}

// ==== finish0: smallT (blocks 0..429) + msg_relu, co-scheduled ==============
__global__ __launch_bounds__(256) void finish0_kernel(
    const float* __restrict__ agg, const float* __restrict__ wr,
    const float* __restrict__ inv0, const float* __restrict__ inv2,
    ushort* __restrict__ G,
    const float* __restrict__ y,
    const int* __restrict__ rp1, const int* __restrict__ csr1, const float* __restrict__ inv1,
    const int* __restrict__ rp3, const int* __restrict__ csr3, const float* __restrict__ inv3)
{
    const int b = blockIdx.x;
    const int t = threadIdx.x;
    if (b < NA + NC) {
        int row = b;
        int c = t;
        const float* a = agg + (size_t)row * D;
        const float* W = wr + (size_t)((row < NA) ? 0 : 2) * DD;
        float scale = (row < NA) ? inv0[row] : inv2[row - NA];
        float acc = 0.f;
        #pragma unroll 8
        for (int k = 0; k < D; ++k) acc += a[k] * W[k * D + c];
        size_t o = (size_t)(NF + row) * D + c;
        G[o] = f2bf(fmaxf(bf2f(G[o]) + scale * acc, 0.f));
        return;
    }
    int wid = ((b - (NA + NC)) * 256 + t) >> 6;
    int lane = t & 63;
    int row = wid * 2 + (lane >> 5);
    if (row >= NF) return;
    int c = (lane & 31) * 8;
    size_t o = (size_t)row * D + c;
    u16x8 gh = *(const u16x8*)(G + o);
    float v[8];
    #pragma unroll
    for (int j = 0; j < 8; ++j) v[j] = bf2f(gh[j]);
    float m[8] = {};
    int e0 = rp1[row], e1 = rp1[row + 1];
    for (int e = e0; e < e1; ++e) {
        const float* yr = y + (size_t)csr1[e] * D + c;
        float4 u0 = *(const float4*)yr;
        float4 u1 = *(const float4*)(yr + 4);
        m[0] += u0.x; m[1] += u0.y; m[2] += u0.z; m[3] += u0.w;
        m[4] += u1.x; m[5] += u1.y; m[6] += u1.z; m[7] += u1.w;
    }
    float s1 = inv1[row];
    #pragma unroll
    for (int j = 0; j < 8; ++j) { v[j] += s1 * m[j]; m[j] = 0.f; }
    e0 = rp3[row]; e1 = rp3[row + 1];
    for (int e = e0; e < e1; ++e) {
        const float* yr = y + (size_t)(NA + csr3[e]) * D + c;
        float4 u0 = *(const float4*)yr;
        float4 u1 = *(const float4*)(yr + 4);
        m[0] += u0.x; m[1] += u0.y; m[2] += u0.z; m[3] += u0.w;
        m[4] += u1.x; m[5] += u1.y; m[6] += u1.z; m[7] += u1.w;
    }
    float s3 = inv3[row];
    u16x8 oh;
    #pragma unroll
    for (int j = 0; j < 8; ++j) oh[j] = f2bf(fmaxf(v[j] + s3 * m[j], 0.f));
    *(u16x8*)(G + o) = oh;
}

// ---- layer-1: out[f] = relu(G2+msgs) . W_out + b_out (fused readout) -------
__global__ __launch_bounds__(256) void msg_readout_kernel(
    const ushort* __restrict__ G,
    const float* __restrict__ y,
    const int* __restrict__ rp1, const int* __restrict__ csr1, const float* __restrict__ inv1,
    const int* __restrict__ rp3, const int* __restrict__ csr3, const float* __restrict__ inv3,
    const float* __restrict__ wout, const float* __restrict__ bout,
    float* __restrict__ out)
{
    int wid = (blockIdx.x * 256 + threadIdx.x) >> 6;
    int lane = threadIdx.x & 63;
    int row = wid * 2 + (lane >> 5);
    if (row >= NF) return;
    int c = (lane & 31) * 8;
    size_t o = (size_t)row * D + c;
    u16x8 gh = *(const u16x8*)(G + o);
    float v[8];
    #pragma unroll
    for (int j = 0; j < 8; ++j) v[j] = bf2f(gh[j]);
    float m[8] = {};
    int e0 = rp1[row], e1 = rp1[row + 1];
    for (int e = e0; e < e1; ++e) {
        const float* yr = y + (size_t)csr1[e] * D + c;
        float4 u0 = *(const float4*)yr;
        float4 u1 = *(const float4*)(yr + 4);
        m[0] += u0.x; m[1] += u0.y; m[2] += u0.z; m[3] += u0.w;
        m[4] += u1.x; m[5] += u1.y; m[6] += u1.z; m[7] += u1.w;
    }
    float s1 = inv1[row];
    #pragma unroll
    for (int j = 0; j < 8; ++j) { v[j] += s1 * m[j]; m[j] = 0.f; }
    e0 = rp3[row]; e1 = rp3[row + 1];
    for (int e = e0; e < e1; ++e) {
        const float* yr = y + (size_t)(NA + csr3[e]) * D + c;
        float4 u0 = *(const float4*)yr;
        float4 u1 = *(const float4*)(yr + 4);
        m[0] += u0.x; m[1] += u0.y; m[2] += u0.z; m[3] += u0.w;
        m[4] += u1.x; m[5] += u1.y; m[6] += u1.z; m[7] += u1.w;
    }
    float s3 = inv3[row];
    float4 w0 = *(const float4*)(wout + c);
    float4 w1 = *(const float4*)(wout + c + 4);
    float wv[8] = {w0.x, w0.y, w0.z, w0.w, w1.x, w1.y, w1.z, w1.w};
    float pr = 0.f;
    #pragma unroll
    for (int j = 0; j < 8; ++j) pr += fmaxf(v[j] + s3 * m[j], 0.f) * wv[j];
    pr += __shfl_xor(pr, 1);
    pr += __shfl_xor(pr, 2);
    pr += __shfl_xor(pr, 4);
    pr += __shfl_xor(pr, 8);
    pr += __shfl_xor(pr, 16);
    if ((lane & 31) == 0) out[row] = pr + bout[0];
}

extern "C" void kernel_launch(void* const* d_in, const int* in_sizes, int n_in,
                              void* d_out, int out_size, void* d_ws, size_t ws_size,
                              hipStream_t stream)
{
    const float* xf = (const float*)d_in[0];
    const float* xa = (const float*)d_in[1];
    const float* xc = (const float*)d_in[2];
    const float* Wf = (const float*)d_in[3];
    const float* bf = (const float*)d_in[4];
    const float* Wa = (const float*)d_in[5];
    const float* ba = (const float*)d_in[6];
    const float* Wc = (const float*)d_in[7];
    const float* bc = (const float*)d_in[8];
    const float* basis0 = (const float*)d_in[9];
    const float* comp0  = (const float*)d_in[10];
    const float* root0  = (const float*)d_in[11];
    const float* bias0  = (const float*)d_in[12];
    const float* basis1 = (const float*)d_in[13];
    const float* comp1  = (const float*)d_in[14];
    const float* root1  = (const float*)d_in[15];
    const float* bias1  = (const float*)d_in[16];
    const float* Wout = (const float*)d_in[17];
    const float* bout = (const float*)d_in[18];
    const int* src0 = (const int*)d_in[19];
    const int* dst0 = (const int*)d_in[20];
    const int* src1 = (const int*)d_in[21];
    const int* dst1 = (const int*)d_in[22];
    const int* src2 = (const int*)d_in[23];
    const int* dst2 = (const int*)d_in[24];
    const int* src3 = (const int*)d_in[25];
    const int* dst3 = (const int*)d_in[26];
    float* out = (float*)d_out;

    char* ws = (char*)d_ws;
    size_t off = 0;
    auto alloc = [&](size_t bytes) -> char* {
        char* p = ws + off;
        off = (off + bytes + 255) & ~(size_t)255;
        return p;
    };
    ushort* hH  = (ushort*)alloc((size_t)NN * D * 2);
    ushort* gH  = (ushort*)alloc((size_t)NN * D * 2);
    // layer-1 GEMM output reuses hH (dead after layer-0 consumers)
    ushort* g2H = hH;
    ushort* WtH0 = (ushort*)alloc((size_t)DD * 2);
    ushort* WtL0 = (ushort*)alloc((size_t)DD * 2);
    ushort* WtH1 = (ushort*)alloc((size_t)DD * 2);
    ushort* WtL1 = (ushort*)alloc((size_t)DD * 2);
    ushort* WfTH = (ushort*)alloc((size_t)D * 32 * 2);
    ushort* WfTL = (ushort*)alloc((size_t)D * 32 * 2);
    float* wr0    = (float*)alloc((size_t)4 * DD * 4);
    float* wr1    = (float*)alloc((size_t)4 * DD * 4);
    float* ybuf   = (float*)alloc((size_t)(NA + NC) * D * 4);
    float* aggbuf = (float*)alloc((size_t)(NA + NC) * D * 4);
    int*   deg13  = (int*)  alloc((size_t)2 * NF * 4);
    int* deg1 = deg13; int* deg3 = deg13 + NF;
    float* inv1 = (float*)alloc((size_t)NF * 4);
    float* inv3 = (float*)alloc((size_t)NF * 4);
    float* inv0 = (float*)alloc((size_t)NA * 4);
    float* inv2 = (float*)alloc((size_t)NC * 4);
    int* rp0 = (int*)alloc((NA + 1) * 4);
    int* rp1 = (int*)alloc((size_t)(NF + 1) * 4);
    int* rp2 = (int*)alloc((NC + 1) * 4);
    int* rp3 = (int*)alloc((size_t)(NF + 1) * 4);
    int* cu1 = (int*)alloc((size_t)(NF + 1) * 4);
    int* cu3 = (int*)alloc((size_t)(NF + 1) * 4);
    int* csr0 = (int*)alloc((size_t)E * 4);
    int* csr1 = (int*)alloc((size_t)E * 4);
    int* csr2 = (int*)alloc((size_t)E * 4);
    int* csr3 = (int*)alloc((size_t)E * 4);
    int* bsum = (int*)alloc(256 * 4);
    int* bh0  = (int*)alloc((size_t)NSL * NA * 4);
    int* bh2  = (int*)alloc((size_t)NSL * NC * 4);
    (void)ws_size; (void)in_sizes; (void)n_in; (void)out_size;

    // deg13 must be zero before prep_kernel's deg_count blocks (stream order)
    hipMemsetAsync(deg13, 0, (size_t)2 * NF * 4, stream);

    // K1: hist02 + deg_count + wsplit(x2) + wr(x2)
    prep_kernel<<<K1_WR1_END, 256, 0, stream>>>(
        dst0, dst2, bh0, bh2, aggbuf, Wf, WfTH, WfTL,
        dst1, dst3, deg1, deg3,
        root0, WtH0, WtL0, root1, WtH1, WtL1,
        basis0, comp0, wr0, basis1, comp1, wr1);

    // K2: scanA + scan02
    scan_kernel<<<197, 1024, 0, stream>>>(
        deg1, deg3, bsum, bh0, bh2, rp0, rp2, inv0, inv2);

    // scanC (standalone: produces cu1/cu3 for fill13)
    scanC_kernel<<<196, 1024, 0, stream>>>(
        deg1, deg3, bsum, rp1, rp3, cu1, cu3, inv1, inv3);

    // work: encoder + tail + csr_fill13 + fill02, all co-scheduled
    work_kernel<<<W_TOTAL, 512, 0, stream>>>(
        xf, WfTH, WfTL, bf, xa, Wa, ba, xc, Wc, bc, hH,
        src1, dst1, src3, dst3, cu1, cu3, csr1, csr3,
        src0, dst0, src2, dst2, bh0, bh2, csr0, csr2);

    // ---- layer 0: {gemm + agg + y} co-scheduled, then finishers
    constexpr int NG0 = ((NN + 127) / 128) * 2;
    layer_kernel<0><<<NG0 + AGGB + YB, 512, 0, stream>>>(
        hH, WtH0, WtL0, bias0, gH, wr0, ybuf,
        rp0, csr0, rp2, csr2, aggbuf);
    finish0_kernel<<<(NA + NC) + (NF / 2 * 64 + 255) / 256, 256, 0, stream>>>(
        aggbuf, wr0, inv0, inv2, gH,
        ybuf, rp1, csr1, inv1, rp3, csr3, inv3);

    // ---- layer 1: {gemm + y} co-scheduled, then fused readout
    constexpr int NG1 = ((NF + 127) / 128) * 2;
    layer_kernel<1><<<NG1 + YB, 512, 0, stream>>>(
        gH, WtH1, WtL1, bias1, g2H, wr1, ybuf,
        nullptr, nullptr, nullptr, nullptr, nullptr);
    msg_readout_kernel<<<(NF / 2 * 64 + 255) / 256, 256, 0, stream>>>(
        g2H, ybuf, rp1, csr1, inv1, rp3, csr3, inv3, Wout, bout, out);
}

// Round 28
// 325.386 us; speedup vs baseline: 1.1950x; 1.0013x over previous
//
#include <hip/hip_runtime.h>
#include <hip/hip_bf16.h>
#include <cstdint>
#include <cstddef>

constexpr int NF = 100000;
constexpr int NA = 400;
constexpr int NC = 30;
constexpr int NN = NF + NA + NC;     // 100430
constexpr int D  = 256;
constexpr int DD = D * D;            // 65536
constexpr int E  = 250000;
constexpr int NSL = 128;             // slices for r0/r2 counting sort
constexpr int FBLK = (NF + 127) / 128;   // 782 flight-encoder blocks
constexpr int TAILB = (NA + NC + 7) / 8; // 54 scalar-tail blocks
constexpr int F13B = (2 * E + 511) / 512; // 977 csr_fill13 blocks (512 thr)
constexpr int AGGB = NA * 4 + NC * 64;    // 3520 agg chunks
constexpr int YB   = (NA + NC) / 2;       // 215 y blocks (2 rows each)

// K1 block ranges
constexpr int K1_HIST_END = 2 * NSL;                       // 256
constexpr int K1_DEG_END  = K1_HIST_END + (2 * E + 255) / 256;  // 2210
constexpr int K1_WS0_END  = K1_DEG_END + 256;              // 2466
constexpr int K1_WS1_END  = K1_WS0_END + 256;              // 2722
constexpr int K1_WR0_END  = K1_WS1_END + 1024;             // 3746
constexpr int K1_WR1_END  = K1_WR0_END + 1024;             // 4770

// work_kernel block ranges: encoder | tail | fill13 | fill02
constexpr int W_ENC_END  = FBLK;                 // 782
constexpr int W_TAIL_END = W_ENC_END + TAILB;    // 836
constexpr int W_F13_END  = W_TAIL_END + F13B;    // 1813
constexpr int W_TOTAL    = W_F13_END + 2 * NSL;  // 2069

typedef __attribute__((ext_vector_type(8))) short bf16x8;
typedef __attribute__((ext_vector_type(4))) float f32x4;
typedef __attribute__((ext_vector_type(8))) ushort u16x8;

__device__ inline ushort f2bf(float f) {
    __hip_bfloat16 h = __float2bfloat16(f);
    return __builtin_bit_cast(ushort, h);
}
__device__ inline float bf2f(ushort u) {
    __hip_bfloat16 h = __builtin_bit_cast(__hip_bfloat16, u);
    return __bfloat162float(h);
}

// async global->LDS, 16B per lane: LDS dest = base + lane*16 (wave-linear)
__device__ inline void gload_lds16(const ushort* g, ushort* l) {
    __builtin_amdgcn_global_load_lds(
        (const __attribute__((address_space(1))) void*)g,
        (__attribute__((address_space(3))) void*)l, 16, 0, 0);
}

// ==== K1: hist02 + deg_count + wsplit(x2) + wr(x2), co-scheduled ============
__global__ __launch_bounds__(256) void prep_kernel(
    const int* __restrict__ dst0, const int* __restrict__ dst2,
    int* __restrict__ bh0, int* __restrict__ bh2,
    float* __restrict__ aggz,
    const float* __restrict__ Wf, ushort* __restrict__ WfTH, ushort* __restrict__ WfTL,
    const int* __restrict__ dst1, const int* __restrict__ dst3,
    int* __restrict__ deg1, int* __restrict__ deg3,
    const float* __restrict__ root0, ushort* __restrict__ WtH0, ushort* __restrict__ WtL0,
    const float* __restrict__ root1, ushort* __restrict__ WtH1, ushort* __restrict__ WtL1,
    const float* __restrict__ basis0, const float* __restrict__ comp0, float* __restrict__ wr0,
    const float* __restrict__ basis1, const float* __restrict__ comp1, float* __restrict__ wr1)
{
    __shared__ int hist[NA];
    const int b = blockIdx.x;
    const int t = threadIdx.x;
    if (b < K1_HIST_END) {
        for (int i = b * 256 + t; i < (NA + NC) * D; i += K1_HIST_END * 256)
            aggz[i] = 0.f;
        if (b < 32) {
            float wv = Wf[(size_t)b * D + t];
            ushort hi = f2bf(wv);
            WfTH[(size_t)t * 32 + b] = hi;
            WfTL[(size_t)t * 32 + b] = f2bf(wv - bf2f(hi));
        }
        bool isR2 = (b >= NSL);
        int sl = isR2 ? b - NSL : b;
        const int* dst = isR2 ? dst2 : dst0;
        int nb = isR2 ? NC : NA;
        for (int i = t; i < nb; i += 256) hist[i] = 0;
        __syncthreads();
        int lo = (int)((long long)E * sl / NSL);
        int hi = (int)((long long)E * (sl + 1) / NSL);
        for (int e = lo + t; e < hi; e += 256)
            atomicAdd(&hist[dst[e]], 1);
        __syncthreads();
        int* bh = isR2 ? (bh2 + sl * NC) : (bh0 + sl * NA);
        for (int i = t; i < nb; i += 256) bh[i] = hist[i];
    } else if (b < K1_DEG_END) {
        int idx = (b - K1_HIST_END) * 256 + t;
        if (idx < 2 * E) {
            if (idx < E) atomicAdd(&deg1[dst1[idx]], 1);
            else         atomicAdd(&deg3[dst3[idx - E]], 1);
        }
    } else if (b < K1_WS0_END) {
        int n = b - K1_DEG_END;
        float w = root0[(size_t)t * D + n];
        ushort hi = f2bf(w);
        WtH0[(size_t)n * D + t] = hi;
        WtL0[(size_t)n * D + t] = f2bf(w - bf2f(hi));
    } else if (b < K1_WS1_END) {
        int n = b - K1_WS0_END;
        float w = root1[(size_t)t * D + n];
        ushort hi = f2bf(w);
        WtH1[(size_t)n * D + t] = hi;
        WtL1[(size_t)n * D + t] = f2bf(w - bf2f(hi));
    } else if (b < K1_WR0_END) {
        int idx = (b - K1_WS1_END) * 256 + t;
        int r = idx >> 16;
        int io = idx & (DD - 1);
        wr0[idx] = comp0[r * 3 + 0] * basis0[io]
                 + comp0[r * 3 + 1] * basis0[DD + io]
                 + comp0[r * 3 + 2] * basis0[2 * DD + io];
    } else {
        int idx = (b - K1_WR0_END) * 256 + t;
        int r = idx >> 16;
        int io = idx & (DD - 1);
        wr1[idx] = comp1[r * 3 + 0] * basis1[io]
                 + comp1[r * 3 + 1] * basis1[DD + io]
                 + comp1[r * 3 + 2] * basis1[2 * DD + io];
    }
}

// ==== K2: scanA (blocks 0..195) + scan02 (block 196), co-scheduled ==========
__global__ __launch_bounds__(1024) void scan_kernel(
    const int* __restrict__ deg1, const int* __restrict__ deg3,
    int* __restrict__ bsum,
    int* __restrict__ bh0, int* __restrict__ bh2,
    int* __restrict__ rp0, int* __restrict__ rp2,
    float* __restrict__ inv0, float* __restrict__ inv2)
{
    __shared__ int s[1024];
    __shared__ int tot[512];
    __shared__ int exc[512];
    const int b = blockIdx.x;
    const int t = threadIdx.x;
    if (b < 196) {
        bool isR3 = (b >= 98);
        const int* deg = isR3 ? deg3 : deg1;
        int chunk = isR3 ? b - 98 : b;
        int i = chunk * 1024 + t;
        int v = (i < NF) ? deg[i] : 0;
        s[t] = v;
        __syncthreads();
        for (int ofs = 512; ofs > 0; ofs >>= 1) {
            if (t < ofs) s[t] += s[t + ofs];
            __syncthreads();
        }
        if (t == 0) bsum[(isR3 ? 128 : 0) + chunk] = s[0];
        return;
    }
    int cnt = 0;
    if (t < NA) {
        int ss = 0;
        for (int sl = 0; sl < NSL; ++sl) {
            int v = bh0[sl * NA + t]; bh0[sl * NA + t] = ss; ss += v;
        }
        cnt = ss;
    } else if (t < NA + NC) {
        int bin = t - NA; int ss = 0;
        for (int sl = 0; sl < NSL; ++sl) {
            int v = bh2[sl * NC + bin]; bh2[sl * NC + bin] = ss; ss += v;
        }
        cnt = ss;
    }
    if (t < 512) tot[t] = cnt;
    __syncthreads();
    for (int ofs = 1; ofs < 512; ofs <<= 1) {
        int v = 0;
        if (t < 512 && t >= ofs) v = tot[t - ofs];
        __syncthreads();
        if (t < 512) tot[t] += v;
        __syncthreads();
    }
    if (t < 512) {
        int ex = tot[t] - cnt;
        if (t < NA) {
            exc[t] = ex;
            rp0[t] = ex;
            inv0[t] = 1.0f / (float)(cnt > 1 ? cnt : 1);
            if (t == 0) { rp0[NA] = E; rp2[NC] = E; }
        } else if (t < NA + NC) {
            exc[t] = ex - E;
            rp2[t - NA] = ex - E;
            inv2[t - NA] = 1.0f / (float)(cnt > 1 ? cnt : 1);
        } else exc[t] = 0;
    }
    __syncthreads();
    for (int idx = t; idx < NSL * NA; idx += 1024) {
        int sl = idx / NA; int bin = idx - sl * NA;
        bh0[idx] += exc[bin];
    }
    for (int idx = t; idx < NSL * NC; idx += 1024) {
        int sl = idx / NC; int bin = idx - sl * NC;
        bh2[idx] += exc[NA + bin];
    }
}

// ==== scanC (with inlined scanB), standalone -------------------------------
__global__ __launch_bounds__(1024) void scanC_kernel(
    const int* __restrict__ deg1, const int* __restrict__ deg3,
    const int* __restrict__ bsum,
    int* __restrict__ rp1, int* __restrict__ rp3,
    int* __restrict__ cu1, int* __restrict__ cu3,
    float* __restrict__ inv1, float* __restrict__ inv3)
{
    __shared__ int s[1024];
    __shared__ int s2[256];
    int t = threadIdx.x;
    int b = blockIdx.x;                    // 0..195
    int vb = 0;
    if (t < 256) {
        vb = ((t & 127) < 98) ? bsum[t] : 0;
        s2[t] = vb;
    }
    __syncthreads();
    for (int ofs = 1; ofs < 128; ofs <<= 1) {
        int a = 0;
        if (t < 256 && (t & 127) >= ofs) a = s2[t - ofs];
        __syncthreads();
        if (t < 256) s2[t] += a;
        __syncthreads();
    }
    if (t < 256) s2[t] -= vb;          // exclusive
    __syncthreads();
    const int* deg; int* rp; int* cu; float* inv; int chunk; int prefix;
    if (b < 98) { deg = deg1; rp = rp1; cu = cu1; inv = inv1; chunk = b;      prefix = s2[chunk]; }
    else        { deg = deg3; rp = rp3; cu = cu3; inv = inv3; chunk = b - 98; prefix = s2[128 + chunk]; }
    int i = chunk * 1024 + t;
    int v = (i < NF) ? deg[i] : 0;
    s[t] = v;
    __syncthreads();
    for (int ofs = 1; ofs < 1024; ofs <<= 1) {
        int a = (t >= ofs) ? s[t - ofs] : 0;
        __syncthreads();
        s[t] += a;
        __syncthreads();
    }
    int ex = prefix + s[t] - v;
    if (i < NF) {
        rp[i] = ex;
        cu[i] = ex;
        inv[i] = 1.0f / (float)(v > 1 ? v : 1);
    }
    if (i == 0) rp[NF] = E;
}

// ==== work_kernel: encoder + tail + csr_fill13 + fill02, co-scheduled =======
__global__ __launch_bounds__(512) void work_kernel(
    const float* __restrict__ xf,
    const ushort* __restrict__ WtH8, const ushort* __restrict__ WtL8,
    const float* __restrict__ bfl,
    const float* __restrict__ xa, const float* __restrict__ Wa, const float* __restrict__ ba,
    const float* __restrict__ xc, const float* __restrict__ Wc, const float* __restrict__ bc,
    ushort* __restrict__ hH,
    const int* __restrict__ src1, const int* __restrict__ dst1,
    const int* __restrict__ src3, const int* __restrict__ dst3,
    int* __restrict__ cu1, int* __restrict__ cu3,
    int* __restrict__ csr1, int* __restrict__ csr3,
    const int* __restrict__ src0, const int* __restrict__ dst0,
    const int* __restrict__ src2, const int* __restrict__ dst2,
    const int* __restrict__ bh0, const int* __restrict__ bh2,
    int* __restrict__ csr0, int* __restrict__ csr2)
{
    __shared__ __align__(16) ushort lds[20480];            // 40960 B
    const int t = threadIdx.x;
    const int b = blockIdx.x;
    if (b >= W_F13_END) {
        // ---- fill02 (512 threads, LDS cursor)
        int bb = b - W_F13_END;
        int* cur = (int*)lds;
        bool isR2 = (bb >= NSL);
        int sl = isR2 ? bb - NSL : bb;
        const int* src = isR2 ? src2 : src0;
        const int* dst = isR2 ? dst2 : dst0;
        const int* bh  = isR2 ? (bh2 + sl * NC) : (bh0 + sl * NA);
        int* csr       = isR2 ? csr2 : csr0;
        int nb = isR2 ? NC : NA;
        for (int i = t; i < nb; i += 512) cur[i] = bh[i];
        __syncthreads();
        int lo = (int)((long long)E * sl / NSL);
        int hi = (int)((long long)E * (sl + 1) / NSL);
        for (int e = lo + t; e < hi; e += 512) {
            int pos = atomicAdd(&cur[dst[e]], 1);
            csr[pos] = src[e];
        }
        return;
    }
    if (b >= W_TAIL_END) {
        // ---- csr_fill13
        int idx = (b - W_TAIL_END) * 512 + t;
        if (idx < 2 * E) {
            if (idx < E) {
                int pos = atomicAdd(&cu1[dst1[idx]], 1);
                csr1[pos] = src1[idx];
            } else {
                int e = idx - E;
                int pos = atomicAdd(&cu3[dst3[e]], 1);
                csr3[pos] = src3[e];
            }
        }
        return;
    }
    if (b >= W_ENC_END) {
        // ---- airports + carriers scalar path
        int c = t & 255;
        int i0 = t >> 8;
        int base = (b - W_ENC_END) * 8;
        for (int i = i0; i < 8; i += 2) {
            int row = base + i;
            if (row >= NA + NC) break;
            float acc;
            if (row < NA) {
                const float* xr = xa + (size_t)row * 16;
                acc = ba[c];
                #pragma unroll
                for (int k = 0; k < 16; ++k) acc += xr[k] * Wa[k * D + c];
            } else {
                const float* xr = xc + (size_t)(row - NA) * 8;
                acc = bc[c];
                #pragma unroll
                for (int k = 0; k < 8; ++k) acc += xr[k] * Wc[k * D + c];
            }
            hH[(size_t)(NF + row) * D + c] = f2bf(fmaxf(acc, 0.f));
        }
        return;
    }
    // ---- flight MFMA encoder
    constexpr int AOFF = 0, WHOFF = 4096, WLOFF = 12288;   // ushort offsets
    const int row0 = b * 128;
    const int w = t >> 6, lane = t & 63;     // 8 waves
    const int wm = w >> 2, wn = w & 3;       // 2x4 grid, 64 rows x 64 cols/wave
    const int lr = lane & 15;
    const int lk = lane >> 4;
    {
        int r = t >> 2;                      // 0..127
        int seg = (t & 3) * 8;               // 0,8,16,24
        int gr = row0 + r; if (gr >= NF) gr = NF - 1;
        const float* xr = xf + (size_t)gr * 32 + seg;
        float4 a0 = *(const float4*)xr;
        float4 a1 = *(const float4*)(xr + 4);
        u16x8 bb;
        bb[0] = f2bf(a0.x); bb[1] = f2bf(a0.y); bb[2] = f2bf(a0.z); bb[3] = f2bf(a0.w);
        bb[4] = f2bf(a1.x); bb[5] = f2bf(a1.y); bb[6] = f2bf(a1.z); bb[7] = f2bf(a1.w);
        int g = r >> 4, rr = r & 15, kg = seg >> 3;
        *(u16x8*)(lds + AOFF + g * 512 + (rr + 16 * kg) * 8) = bb;
    }
    #pragma unroll
    for (int i = 0; i < 4; ++i) {
        int u = w * 4 + i;                   // 0..31
        int plane = u >> 4, g = u & 15;
        const ushort* src = (plane ? WtL8 : WtH8) + ((size_t)(g * 16 + lr)) * 32 + lk * 8;
        ushort* dst = lds + (plane ? WLOFF : WHOFF) + g * 512;
        gload_lds16(src, dst);
    }
    __syncthreads();
    f32x4 acc[4][4] = {};
    bf16x8 bhv[4], blv[4];
    #pragma unroll
    for (int ni = 0; ni < 4; ++ni) {
        int off = (wn * 4 + ni) * 512 + lane * 8;
        bhv[ni] = *(const bf16x8*)(lds + WHOFF + off);
        blv[ni] = *(const bf16x8*)(lds + WLOFF + off);
    }
    #pragma unroll
    for (int mi = 0; mi < 4; ++mi) {
        bf16x8 ah = *(const bf16x8*)(lds + AOFF + (wm * 4 + mi) * 512 + lane * 8);
        #pragma unroll
        for (int ni = 0; ni < 4; ++ni) {
            acc[mi][ni] = __builtin_amdgcn_mfma_f32_16x16x32_bf16(ah, bhv[ni], acc[mi][ni], 0, 0, 0);
            acc[mi][ni] = __builtin_amdgcn_mfma_f32_16x16x32_bf16(ah, blv[ni], acc[mi][ni], 0, 0, 0);
        }
    }
    // Epilogue: per-wave PRIVATE LDS scratch (S regions are disjoint across
    // waves); one barrier guards the A/W staging reads above, then no
    // further barriers needed (intra-wave write->read only).
    constexpr int ELDW = 68;
    float* S = (float*)lds + (size_t)w * 16 * ELDW;
    const int rrow = lane >> 3;
    const int grp  = lane & 7;
    __syncthreads();
    #pragma unroll
    for (int mi = 0; mi < 4; ++mi) {
        #pragma unroll
        for (int ni = 0; ni < 4; ++ni)
            #pragma unroll
            for (int reg = 0; reg < 4; ++reg)
                S[(lk * 4 + reg) * ELDW + ni * 16 + lr] = acc[mi][ni][reg];
        #pragma unroll
        for (int it = 0; it < 2; ++it) {
            int row_i = rrow + it * 8;
            int gr = row0 + wm * 64 + mi * 16 + row_i;
            int gc = wn * 64 + grp * 8;
            if (gr >= NF) continue;
            float4 f0 = *(const float4*)(&S[row_i * ELDW + grp * 8]);
            float4 f1 = *(const float4*)(&S[row_i * ELDW + grp * 8 + 4]);
            float4 b0 = *(const float4*)(bfl + gc);
            float4 b1 = *(const float4*)(bfl + gc + 4);
            u16x8 hh;
            hh[0] = f2bf(fmaxf(f0.x + b0.x, 0.f));
            hh[1] = f2bf(fmaxf(f0.y + b0.y, 0.f));
            hh[2] = f2bf(fmaxf(f0.z + b0.z, 0.f));
            hh[3] = f2bf(fmaxf(f0.w + b0.w, 0.f));
            hh[4] = f2bf(fmaxf(f1.x + b1.x, 0.f));
            hh[5] = f2bf(fmaxf(f1.y + b1.y, 0.f));
            hh[6] = f2bf(fmaxf(f1.z + b1.z, 0.f));
            hh[7] = f2bf(fmaxf(f1.w + b1.w, 0.f));
            *(u16x8*)(hH + (size_t)gr * D + gc) = hh;
        }
    }
}

// ==== layer kernel: gemm tiles + (MODE 0: agg chunks) + y rows, co-sched ====
// gemm block decode uses an XCD-pairing swizzle: the two column tiles of one
// row tile get blockIdx values differing by exactly 8 (same XCD under
// round-robin dispatch) so the shared 64 KB A panel is an L2 hit on reuse.
template<int MODE>
__global__ __launch_bounds__(512) void layer_kernel(
    const ushort* __restrict__ A,
    const ushort* __restrict__ WtH, const ushort* __restrict__ WtL,
    const float* __restrict__ bias, ushort* __restrict__ G,
    const float* __restrict__ wr, float* __restrict__ y,
    const int* __restrict__ rp0, const int* __restrict__ csr0,
    const int* __restrict__ rp2, const int* __restrict__ csr2,
    float* __restrict__ agg)
{
    constexpr int BM = 128, BK = 32;
    constexpr int PLANE = BM * BK;          // 4096 ushorts = 8 KB
    constexpr int BUF = 3 * PLANE;          // 12288 ushorts = 24 KB
    constexpr int LDW = 36;                 // fp32 epilogue scratch stride
    constexpr int nrows = (MODE == 0) ? NN : NF;
    constexpr int NT = (nrows + 127) / 128;   // row tiles
    constexpr int NG = NT * 2;
    constexpr int G8 = (NT / 8) * 16;         // full swizzle groups
    constexpr int NAGG = (MODE == 0) ? AGGB : 0;
    __shared__ __align__(16) ushort lds[2 * BUF];   // 49152 B
    const int t = threadIdx.x;
    const int b = blockIdx.x;
    if (b >= NG) {
        int bb = b - NG;
        if (MODE == 0 && bb < NAGG) {
            float* red = (float*)lds;        // 8 x 256 floats
            const int* rp; const int* csr; int dstn, chunk, nch; float* arow;
            if (bb < NA * 4) { dstn = bb >> 2; chunk = bb & 3; nch = 4;  rp = rp0; csr = csr0; arow = agg + (size_t)dstn * D; }
            else { int b2 = bb - NA * 4; dstn = b2 >> 6; chunk = b2 & 63; nch = 64; rp = rp2; csr = csr2; arow = agg + (size_t)(NA + dstn) * D; }
            int s = rp[dstn], e = rp[dstn + 1];
            int cnt = e - s;
            int lo = s + (int)((long long)cnt * chunk / nch);
            int hi = s + (int)((long long)cnt * (chunk + 1) / nch);
            int w8 = t >> 6, lane = t & 63;
            int span = hi - lo;
            int wlo = lo + (int)((long long)span * w8 / 8);
            int whi = lo + (int)((long long)span * (w8 + 1) / 8);
            int half = lane >> 5;
            int ch8 = (lane & 31) * 8;
            float acc[8] = {};
            int p = wlo;
            for (; p + 1 < whi; p += 2) {
                int r = csr[p + half];
                u16x8 v = *(const u16x8*)(A + (size_t)r * D + ch8);
                #pragma unroll
                for (int j = 0; j < 8; ++j) acc[j] += bf2f(v[j]);
            }
            if (p < whi && half == 0) {
                int r = csr[p];
                u16x8 v = *(const u16x8*)(A + (size_t)r * D + ch8);
                #pragma unroll
                for (int j = 0; j < 8; ++j) acc[j] += bf2f(v[j]);
            }
            #pragma unroll
            for (int j = 0; j < 8; ++j) acc[j] += __shfl_xor(acc[j], 32);
            if (lane < 32) {
                #pragma unroll
                for (int j = 0; j < 8; ++j) red[w8 * 256 + ch8 + j] = acc[j];
            }
            __syncthreads();
            if (t < 256) {
                float total = 0.f;
                #pragma unroll
                for (int j = 0; j < 8; ++j) total += red[j * 256 + t];
                atomicAdd(arow + t, total);
            }
            return;
        }
        int yb = bb - NAGG;
        int row = yb * 2 + (t >> 8);
        if (row < NA + NC) {
            int c = t & 255;
            const ushort* sH = A + (size_t)(NF + row) * D;
            const float* W = wr + (size_t)((row < NA) ? 1 : 3) * DD;
            float acc = 0.f;
            #pragma unroll 8
            for (int k = 0; k < D; ++k) acc += bf2f(sH[k]) * W[k * D + c];
            y[(size_t)row * D + c] = acc;
        }
        return;
    }
    // ---- gemm tile with XCD-pairing swizzle (bijective incl. tail) ----
    int rtile, ctile;
    if (b < G8) {
        int g = b >> 4, j = b & 15;
        rtile = g * 8 + (j & 7);
        ctile = j >> 3;
    } else {
        int j = b - G8;
        rtile = (NT / 8) * 8 + (j >> 1);
        ctile = j & 1;
    }
    const int row0 = rtile * BM;
    const int col0 = ctile * BM;
    const int w = t >> 6, lane = t & 63;    // 8 waves
    const int wm = w >> 2, wn = w & 3;      // 2x4 wave grid, 64x32 per wave
    const int lr = lane & 15;
    const int lk = lane >> 4;
    f32x4 acc[4][2] = {};

    const ushort* sp[3];
    int dofs[3];
    #pragma unroll
    for (int i = 0; i < 3; ++i) {
        int idx = w * 3 + i;
        int plane = idx >> 3, g = idx & 7;
        const ushort* base = (plane == 0) ? A : (plane == 1) ? WtH : WtL;
        int r = ((plane == 0) ? row0 : col0) + g * 16 + lr;
        if (plane == 0 && r >= nrows) r = nrows - 1;
        sp[i] = base + (size_t)r * D + lk * 8;
        dofs[i] = plane * PLANE + g * 512;
    }

    auto stage = [&](int kt, int buf) {
        ushort* bb2 = lds + buf * BUF;
        int k0 = kt * BK;
        #pragma unroll
        for (int i = 0; i < 3; ++i)
            gload_lds16(sp[i] + k0, bb2 + dofs[i]);
    };
    auto compute = [&](int buf) {
        const ushort* base = lds + buf * BUF;
        const ushort* As  = base;
        const ushort* WsH = base + PLANE;
        const ushort* WsL = base + 2 * PLANE;
        bf16x8 bh[2], bl[2];
        #pragma unroll
        for (int ni = 0; ni < 2; ++ni) {
            int off = (wn * 2 + ni) * 512 + lane * 8;
            bh[ni] = *(const bf16x8*)(&WsH[off]);
            bl[ni] = *(const bf16x8*)(&WsL[off]);
        }
        #pragma unroll
        for (int mi = 0; mi < 4; ++mi) {
            int off = (wm * 4 + mi) * 512 + lane * 8;
            bf16x8 ah = *(const bf16x8*)(&As[off]);
            #pragma unroll
            for (int ni = 0; ni < 2; ++ni) {
                acc[mi][ni] = __builtin_amdgcn_mfma_f32_16x16x32_bf16(ah, bh[ni], acc[mi][ni], 0, 0, 0);
                acc[mi][ni] = __builtin_amdgcn_mfma_f32_16x16x32_bf16(ah, bl[ni], acc[mi][ni], 0, 0, 0);
            }
        }
    };

    stage(0, 0);
    stage(1, 1);
#define PIPE_ITER(KT, PEND)                                        \
    asm volatile("s_waitcnt vmcnt(" #PEND ")" ::: "memory");       \
    __builtin_amdgcn_s_barrier();                                  \
    __builtin_amdgcn_sched_barrier(0);                             \
    compute((KT) & 1);                                             \
    __builtin_amdgcn_s_barrier();                                  \
    __builtin_amdgcn_sched_barrier(0);                             \
    if ((KT) + 2 < 8) stage((KT) + 2, (KT) & 1);
    PIPE_ITER(0, 3)
    PIPE_ITER(1, 3)
    PIPE_ITER(2, 3)
    PIPE_ITER(3, 3)
    PIPE_ITER(4, 3)
    PIPE_ITER(5, 3)
    PIPE_ITER(6, 3)
    PIPE_ITER(7, 0)
#undef PIPE_ITER

    // Epilogue: per-wave PRIVATE LDS scratch (16x36 fp32 per wave, disjoint);
    // the final PIPE_ITER barrier already separates all waves' LDS reads from
    // these writes, and write->read below is intra-wave only -> no barriers.
    __syncthreads();                         // conservative: buffers now dead
    float* S = (float*)lds + (size_t)w * 16 * LDW;   // per-wave 16x36 fp32
    const int rrow = lane >> 2;            // 0..15 read-back row
    const int grp  = lane & 3;             // col octet (8 bf16)
    #pragma unroll
    for (int mi = 0; mi < 4; ++mi) {
        #pragma unroll
        for (int ni = 0; ni < 2; ++ni)
            #pragma unroll
            for (int reg = 0; reg < 4; ++reg)
                S[(lk * 4 + reg) * LDW + ni * 16 + lr] = acc[mi][ni][reg];
        int gr = row0 + wm * 64 + mi * 16 + rrow;
        int gc = col0 + wn * 32 + grp * 8;
        if (gr >= nrows) continue;
        float4 f0 = *(const float4*)(&S[rrow * LDW + grp * 8]);
        float4 f1 = *(const float4*)(&S[rrow * LDW + grp * 8 + 4]);
        float4 b0 = *(const float4*)(bias + gc);
        float4 b1 = *(const float4*)(bias + gc + 4);
        float v[8] = {f0.x + b0.x, f0.y + b0.y, f0.z + b0.z, f0.w + b0.w,
                      f1.x + b1.x, f1.y + b1.y, f1.z + b1.z, f1.w + b1.w};
        u16x8 hh;
        #pragma unroll
        for (int j = 0; j < 8; ++j) hh[j] = f2bf(v[j]);
        *(u16x8*)(G + (size_t)gr * D + gc) = hh;
    }
}

// ==== finish0: smallT (blocks 0..429) + msg_relu, co-scheduled ==============
__global__ __launch_bounds__(256) void finish0_kernel(
    const float* __restrict__ agg, const float* __restrict__ wr,
    const float* __restrict__ inv0, const float* __restrict__ inv2,
    ushort* __restrict__ G,
    const float* __restrict__ y,
    const int* __restrict__ rp1, const int* __restrict__ csr1, const float* __restrict__ inv1,
    const int* __restrict__ rp3, const int* __restrict__ csr3, const float* __restrict__ inv3)
{
    const int b = blockIdx.x;
    const int t = threadIdx.x;
    if (b < NA + NC) {
        int row = b;
        int c = t;
        const float* a = agg + (size_t)row * D;
        const float* W = wr + (size_t)((row < NA) ? 0 : 2) * DD;
        float scale = (row < NA) ? inv0[row] : inv2[row - NA];
        float acc = 0.f;
        #pragma unroll 8
        for (int k = 0; k < D; ++k) acc += a[k] * W[k * D + c];
        size_t o = (size_t)(NF + row) * D + c;
        G[o] = f2bf(fmaxf(bf2f(G[o]) + scale * acc, 0.f));
        return;
    }
    int wid = ((b - (NA + NC)) * 256 + t) >> 6;
    int lane = t & 63;
    int row = wid * 2 + (lane >> 5);
    if (row >= NF) return;
    int c = (lane & 31) * 8;
    size_t o = (size_t)row * D + c;
    u16x8 gh = *(const u16x8*)(G + o);
    float v[8];
    #pragma unroll
    for (int j = 0; j < 8; ++j) v[j] = bf2f(gh[j]);
    float m[8] = {};
    int e0 = rp1[row], e1 = rp1[row + 1];
    for (int e = e0; e < e1; ++e) {
        const float* yr = y + (size_t)csr1[e] * D + c;
        float4 u0 = *(const float4*)yr;
        float4 u1 = *(const float4*)(yr + 4);
        m[0] += u0.x; m[1] += u0.y; m[2] += u0.z; m[3] += u0.w;
        m[4] += u1.x; m[5] += u1.y; m[6] += u1.z; m[7] += u1.w;
    }
    float s1 = inv1[row];
    #pragma unroll
    for (int j = 0; j < 8; ++j) { v[j] += s1 * m[j]; m[j] = 0.f; }
    e0 = rp3[row]; e1 = rp3[row + 1];
    for (int e = e0; e < e1; ++e) {
        const float* yr = y + (size_t)(NA + csr3[e]) * D + c;
        float4 u0 = *(const float4*)yr;
        float4 u1 = *(const float4*)(yr + 4);
        m[0] += u0.x; m[1] += u0.y; m[2] += u0.z; m[3] += u0.w;
        m[4] += u1.x; m[5] += u1.y; m[6] += u1.z; m[7] += u1.w;
    }
    float s3 = inv3[row];
    u16x8 oh;
    #pragma unroll
    for (int j = 0; j < 8; ++j) oh[j] = f2bf(fmaxf(v[j] + s3 * m[j], 0.f));
    *(u16x8*)(G + o) = oh;
}

// ---- layer-1: out[f] = relu(G2+msgs) . W_out + b_out (fused readout) -------
__global__ __launch_bounds__(256) void msg_readout_kernel(
    const ushort* __restrict__ G,
    const float* __restrict__ y,
    const int* __restrict__ rp1, const int* __restrict__ csr1, const float* __restrict__ inv1,
    const int* __restrict__ rp3, const int* __restrict__ csr3, const float* __restrict__ inv3,
    const float* __restrict__ wout, const float* __restrict__ bout,
    float* __restrict__ out)
{
    int wid = (blockIdx.x * 256 + threadIdx.x) >> 6;
    int lane = threadIdx.x & 63;
    int row = wid * 2 + (lane >> 5);
    if (row >= NF) return;
    int c = (lane & 31) * 8;
    size_t o = (size_t)row * D + c;
    u16x8 gh = *(const u16x8*)(G + o);
    float v[8];
    #pragma unroll
    for (int j = 0; j < 8; ++j) v[j] = bf2f(gh[j]);
    float m[8] = {};
    int e0 = rp1[row], e1 = rp1[row + 1];
    for (int e = e0; e < e1; ++e) {
        const float* yr = y + (size_t)csr1[e] * D + c;
        float4 u0 = *(const float4*)yr;
        float4 u1 = *(const float4*)(yr + 4);
        m[0] += u0.x; m[1] += u0.y; m[2] += u0.z; m[3] += u0.w;
        m[4] += u1.x; m[5] += u1.y; m[6] += u1.z; m[7] += u1.w;
    }
    float s1 = inv1[row];
    #pragma unroll
    for (int j = 0; j < 8; ++j) { v[j] += s1 * m[j]; m[j] = 0.f; }
    e0 = rp3[row]; e1 = rp3[row + 1];
    for (int e = e0; e < e1; ++e) {
        const float* yr = y + (size_t)(NA + csr3[e]) * D + c;
        float4 u0 = *(const float4*)yr;
        float4 u1 = *(const float4*)(yr + 4);
        m[0] += u0.x; m[1] += u0.y; m[2] += u0.z; m[3] += u0.w;
        m[4] += u1.x; m[5] += u1.y; m[6] += u1.z; m[7] += u1.w;
    }
    float s3 = inv3[row];
    float4 w0 = *(const float4*)(wout + c);
    float4 w1 = *(const float4*)(wout + c + 4);
    float wv[8] = {w0.x, w0.y, w0.z, w0.w, w1.x, w1.y, w1.z, w1.w};
    float pr = 0.f;
    #pragma unroll
    for (int j = 0; j < 8; ++j) pr += fmaxf(v[j] + s3 * m[j], 0.f) * wv[j];
    pr += __shfl_xor(pr, 1);
    pr += __shfl_xor(pr, 2);
    pr += __shfl_xor(pr, 4);
    pr += __shfl_xor(pr, 8);
    pr += __shfl_xor(pr, 16);
    if ((lane & 31) == 0) out[row] = pr + bout[0];
}

extern "C" void kernel_launch(void* const* d_in, const int* in_sizes, int n_in,
                              void* d_out, int out_size, void* d_ws, size_t ws_size,
                              hipStream_t stream)
{
    const float* xf = (const float*)d_in[0];
    const float* xa = (const float*)d_in[1];
    const float* xc = (const float*)d_in[2];
    const float* Wf = (const float*)d_in[3];
    const float* bf = (const float*)d_in[4];
    const float* Wa = (const float*)d_in[5];
    const float* ba = (const float*)d_in[6];
    const float* Wc = (const float*)d_in[7];
    const float* bc = (const float*)d_in[8];
    const float* basis0 = (const float*)d_in[9];
    const float* comp0  = (const float*)d_in[10];
    const float* root0  = (const float*)d_in[11];
    const float* bias0  = (const float*)d_in[12];
    const float* basis1 = (const float*)d_in[13];
    const float* comp1  = (const float*)d_in[14];
    const float* root1  = (const float*)d_in[15];
    const float* bias1  = (const float*)d_in[16];
    const float* Wout = (const float*)d_in[17];
    const float* bout = (const float*)d_in[18];
    const int* src0 = (const int*)d_in[19];
    const int* dst0 = (const int*)d_in[20];
    const int* src1 = (const int*)d_in[21];
    const int* dst1 = (const int*)d_in[22];
    const int* src2 = (const int*)d_in[23];
    const int* dst2 = (const int*)d_in[24];
    const int* src3 = (const int*)d_in[25];
    const int* dst3 = (const int*)d_in[26];
    float* out = (float*)d_out;

    char* ws = (char*)d_ws;
    size_t off = 0;
    auto alloc = [&](size_t bytes) -> char* {
        char* p = ws + off;
        off = (off + bytes + 255) & ~(size_t)255;
        return p;
    };
    ushort* hH  = (ushort*)alloc((size_t)NN * D * 2);
    ushort* gH  = (ushort*)alloc((size_t)NN * D * 2);
    // layer-1 GEMM output reuses hH (dead after layer-0 consumers)
    ushort* g2H = hH;
    ushort* WtH0 = (ushort*)alloc((size_t)DD * 2);
    ushort* WtL0 = (ushort*)alloc((size_t)DD * 2);
    ushort* WtH1 = (ushort*)alloc((size_t)DD * 2);
    ushort* WtL1 = (ushort*)alloc((size_t)DD * 2);
    ushort* WfTH = (ushort*)alloc((size_t)D * 32 * 2);
    ushort* WfTL = (ushort*)alloc((size_t)D * 32 * 2);
    float* wr0    = (float*)alloc((size_t)4 * DD * 4);
    float* wr1    = (float*)alloc((size_t)4 * DD * 4);
    float* ybuf   = (float*)alloc((size_t)(NA + NC) * D * 4);
    float* aggbuf = (float*)alloc((size_t)(NA + NC) * D * 4);
    int*   deg13  = (int*)  alloc((size_t)2 * NF * 4);
    int* deg1 = deg13; int* deg3 = deg13 + NF;
    float* inv1 = (float*)alloc((size_t)NF * 4);
    float* inv3 = (float*)alloc((size_t)NF * 4);
    float* inv0 = (float*)alloc((size_t)NA * 4);
    float* inv2 = (float*)alloc((size_t)NC * 4);
    int* rp0 = (int*)alloc((NA + 1) * 4);
    int* rp1 = (int*)alloc((size_t)(NF + 1) * 4);
    int* rp2 = (int*)alloc((NC + 1) * 4);
    int* rp3 = (int*)alloc((size_t)(NF + 1) * 4);
    int* cu1 = (int*)alloc((size_t)(NF + 1) * 4);
    int* cu3 = (int*)alloc((size_t)(NF + 1) * 4);
    int* csr0 = (int*)alloc((size_t)E * 4);
    int* csr1 = (int*)alloc((size_t)E * 4);
    int* csr2 = (int*)alloc((size_t)E * 4);
    int* csr3 = (int*)alloc((size_t)E * 4);
    int* bsum = (int*)alloc(256 * 4);
    int* bh0  = (int*)alloc((size_t)NSL * NA * 4);
    int* bh2  = (int*)alloc((size_t)NSL * NC * 4);
    (void)ws_size; (void)in_sizes; (void)n_in; (void)out_size;

    // deg13 must be zero before prep_kernel's deg_count blocks (stream order)
    hipMemsetAsync(deg13, 0, (size_t)2 * NF * 4, stream);

    // K1: hist02 + deg_count + wsplit(x2) + wr(x2)
    prep_kernel<<<K1_WR1_END, 256, 0, stream>>>(
        dst0, dst2, bh0, bh2, aggbuf, Wf, WfTH, WfTL,
        dst1, dst3, deg1, deg3,
        root0, WtH0, WtL0, root1, WtH1, WtL1,
        basis0, comp0, wr0, basis1, comp1, wr1);

    // K2: scanA + scan02
    scan_kernel<<<197, 1024, 0, stream>>>(
        deg1, deg3, bsum, bh0, bh2, rp0, rp2, inv0, inv2);

    // scanC (standalone: produces cu1/cu3 for fill13)
    scanC_kernel<<<196, 1024, 0, stream>>>(
        deg1, deg3, bsum, rp1, rp3, cu1, cu3, inv1, inv3);

    // work: encoder + tail + csr_fill13 + fill02, all co-scheduled
    work_kernel<<<W_TOTAL, 512, 0, stream>>>(
        xf, WfTH, WfTL, bf, xa, Wa, ba, xc, Wc, bc, hH,
        src1, dst1, src3, dst3, cu1, cu3, csr1, csr3,
        src0, dst0, src2, dst2, bh0, bh2, csr0, csr2);

    // ---- layer 0: {gemm + agg + y} co-scheduled, then finishers
    constexpr int NG0 = ((NN + 127) / 128) * 2;
    layer_kernel<0><<<NG0 + AGGB + YB, 512, 0, stream>>>(
        hH, WtH0, WtL0, bias0, gH, wr0, ybuf,
        rp0, csr0, rp2, csr2, aggbuf);
    finish0_kernel<<<(NA + NC) + (NF / 2 * 64 + 255) / 256, 256, 0, stream>>>(
        aggbuf, wr0, inv0, inv2, gH,
        ybuf, rp1, csr1, inv1, rp3, csr3, inv3);

    // ---- layer 1: {gemm + y} co-scheduled, then fused readout
    constexpr int NG1 = ((NF + 127) / 128) * 2;
    layer_kernel<1><<<NG1 + YB, 512, 0, stream>>>(
        gH, WtH1, WtL1, bias1, g2H, wr1, ybuf,
        nullptr, nullptr, nullptr, nullptr, nullptr);
    msg_readout_kernel<<<(NF / 2 * 64 + 255) / 256, 256, 0, stream>>>(
        g2H, ybuf, rp1, csr1, inv1, rp3, csr3, inv3, Wout, bout, out);
}